// Round 1
// 504.650 us; speedup vs baseline: 1.5317x; 1.5317x over previous
//
#include <hip/hip_runtime.h>
#include <stdint.h>

typedef __bf16 bf16;
typedef __bf16 bf16x8 __attribute__((ext_vector_type(8)));
typedef __bf16 bf16x4 __attribute__((ext_vector_type(4)));
typedef float  f32x4  __attribute__((ext_vector_type(4)));

#define NB   4096   // sequence length
#define DB   1024   // model dim
#define RV   64     // low rank
#define MB   16384  // B*N

// ---- dtype detection (verified working, rounds 4-5) ----
__global__ void detect_dtype(const unsigned short* x, int* flag) {
  __shared__ int cnt;
  if (threadIdx.x == 0) cnt = 0;
  __syncthreads();
  int local = 0;
  for (int i = threadIdx.x; i < 8192; i += 256) {
    const int e = (x[i] >> 7) & 0xFF;
    if (e >= 0xC0) local++;
  }
  atomicAdd(&cnt, local);
  __syncthreads();
  if (threadIdx.x == 0) *flag = (cnt > 64) ? 1 : 0;  // 1 => inputs are f32
}

// ---- one dispatch converts all 8 input tensors ----
struct CvtArgs {
  const void* src[8];
  bf16* dst[8];
  int n[8];
  int off[9];   // block-range prefix sums
};
__global__ void to_bf16_multi(CvtArgs a, const int* __restrict__ flag) {
  const int blk = blockIdx.x;
  int seg = 0;
#pragma unroll
  for (int s = 1; s < 8; ++s) seg += (blk >= a.off[s]);
  const int i = (blk - a.off[seg]) * 2048 + threadIdx.x * 8;
  if (i >= a.n[seg]) return;
  bf16* dst = a.dst[seg];
  if (*flag) {
    const float* s = (const float*)a.src[seg] + i;
    f32x4 x0 = *(const f32x4*)s;
    f32x4 x1 = *(const f32x4*)(s + 4);
    bf16x8 v;
    v[0]=(bf16)x0[0]; v[1]=(bf16)x0[1]; v[2]=(bf16)x0[2]; v[3]=(bf16)x0[3];
    v[4]=(bf16)x1[0]; v[5]=(bf16)x1[1]; v[6]=(bf16)x1[2]; v[7]=(bf16)x1[3];
    *(bf16x8*)(dst + i) = v;
  } else {
    *(uint4*)(dst + i) = *(const uint4*)((const bf16*)a.src[seg] + i);
  }
}

__global__ void cvt_f32_bf16(const float* __restrict__ src, bf16* __restrict__ dst, int n) {
  const int i = (blockIdx.x * 256 + threadIdx.x) * 8;
  if (i >= n) return;
  f32x4 a = *(const f32x4*)(src + i);
  f32x4 b = *(const f32x4*)(src + i + 4);
  bf16x8 v;
  v[0]=(bf16)a[0]; v[1]=(bf16)a[1]; v[2]=(bf16)a[2]; v[3]=(bf16)a[3];
  v[4]=(bf16)b[0]; v[5]=(bf16)b[1]; v[6]=(bf16)b[2]; v[7]=(bf16)b[3];
  *(bf16x8*)(dst + i) = v;
}

__global__ void zero_f4(float* p) {
  f32x4 z = {0.f, 0.f, 0.f, 0.f};
  ((f32x4*)p)[blockIdx.x*256 + threadIdx.x] = z;
}

// async global->LDS, 16B per lane, wave-uniform LDS base
typedef __attribute__((address_space(1))) const void g_as1_void;
typedef __attribute__((address_space(3))) void as3_void;
static __device__ __forceinline__ void gload16(const void* g, void* l) {
  __builtin_amdgcn_global_load_lds((g_as1_void*)g, (as3_void*)l, 16, 0, 0);
}

struct GemmArgs {
  const bf16* A;
  const bf16* B;
  void* C;
  const bf16* bias;
  const int* oflag;    // runtime f32-out flag (nullable)
  int force_f32;
  int M, N, K;
};

// C[m,n] = sum_k A[m,k]*B[n,k] (+bias[n]); fp32 accum.
// 256x256 tile, BK=64, 512 threads (8 waves, 2m x 4n), double-buffered
// global_load_lds (dwordx4) with pre-swizzled global source + XOR-swizzled
// LDS reads (linear LDS dest, rule both-sides-or-neither).
// REQUIRES: M%256==0, N%256==0, K%128==0 (true for all launches here).
// XCD remap (big grids, gridDim.y==64): each XCD owns an exclusive
// 8-m-tile slab (A never fetched by two XCDs); B (2 MiB) L2-resident.
__global__ __launch_bounds__(512, 2) void gemm_nt(GemmArgs args) {
  const int K = args.K, N = args.N;
  __shared__ __align__(16) char smem[131072];
  bf16* const sA0 = (bf16*)smem;
  bf16* const sB0 = (bf16*)(smem + 32768);
  bf16* const sA1 = (bf16*)(smem + 65536);
  bf16* const sB1 = (bf16*)(smem + 98304);

  const int t = threadIdx.x;
  const int lane = t & 63;
  const int w = t >> 6;
  const int lr = lane & 15;
  const int quad = lane >> 4;
  const int wm = (w >> 2) * 128;   // 0 or 128
  const int wn = (w & 3) * 64;     // 0,64,128,192

  int bx = blockIdx.x, by = blockIdx.y;
  if (gridDim.y == 64) {           // big-GEMM remap: 256 blocks, 8 XCDs
    const int l = by * 4 + bx;     // dispatch order (x fastest)
    const int xcd = l & 7, s = l >> 3;   // s in [0,32)
    by = xcd * 8 + (s >> 2);       // XCD-exclusive 8-m-tile slab
    bx = s & 3;                    // n-fastest within slab
  }
  const int m0 = by * 256;
  const int n0 = bx * 256;

  // staging addressing: 4 gload16 per tensor per K-tile.
  // c = (i*8+w)*64+lane -> row=c>>3, ch=c&7; LDS linear at c*16B;
  // source col-chunk = ch ^ (row&7)  (inverse of the read-side XOR).
  const bf16* gA[4];
  const bf16* gB[4];
  int lds_off[4];                  // bf16 elements
#pragma unroll
  for (int i = 0; i < 4; ++i) {
    const int c = (i*8 + w)*64 + lane;
    const int row = c >> 3, ch = c & 7;
    const int sc = ch ^ (row & 7);
    gA[i] = args.A + (size_t)(m0 + row)*K + sc*8;
    gB[i] = args.B + (size_t)(n0 + row)*K + sc*8;
    lds_off[i] = (i*8 + w) * 512;  // 1024 B per wave-instruction
  }

  auto stage = [&](bf16* dA, bf16* dB, int kt) {
#pragma unroll
    for (int i = 0; i < 4; ++i) gload16(gA[i] + kt, dA + lds_off[i]);
#pragma unroll
    for (int i = 0; i < 4; ++i) gload16(gB[i] + kt, dB + lds_off[i]);
  };

  f32x4 acc[8][4] = {};
  auto compute = [&](const bf16* bA, const bf16* bB) {
#pragma unroll
    for (int ks = 0; ks < 2; ++ks) {
      const int kc = ks*4 + quad;
      bf16x8 af[8], bv[4];
#pragma unroll
      for (int mi = 0; mi < 8; ++mi) {
        const int m = wm + mi*16 + lr;
        af[mi] = *(const bf16x8*)(bA + (m*8 + (kc ^ (m & 7)))*8);
      }
#pragma unroll
      for (int ni = 0; ni < 4; ++ni) {
        const int n = wn + ni*16 + lr;
        bv[ni] = *(const bf16x8*)(bB + (n*8 + (kc ^ (n & 7)))*8);
      }
#pragma unroll
      for (int mi = 0; mi < 8; ++mi)
#pragma unroll
        for (int ni = 0; ni < 4; ++ni)
          acc[mi][ni] = __builtin_amdgcn_mfma_f32_16x16x32_bf16(
              af[mi], bv[ni], acc[mi][ni], 0, 0, 0);
    }
  };

  // prologue
  stage(sA0, sB0, 0);
  asm volatile("s_waitcnt vmcnt(0)" ::: "memory");
  __syncthreads();

  // minimum-2-phase: issue next-tile DMA, compute current, one drain+barrier
  for (int kt = 0; kt < K; kt += 128) {
    stage(sA1, sB1, kt + 64);
    compute(sA0, sB0);
    asm volatile("s_waitcnt vmcnt(0)" ::: "memory");
    __syncthreads();
    if (kt + 128 < K) stage(sA0, sB0, kt + 128);
    compute(sA1, sB1);
    asm volatile("s_waitcnt vmcnt(0)" ::: "memory");
    __syncthreads();
  }

  // epilogue: per-wave 16 KiB LDS patch (64x64 f32), wide 16-B stores.
  // No barriers needed: each wave touches only its own patch; K-loop ended
  // with a barrier.
  const int f32out = args.force_f32 | (args.oflag ? *args.oflag : 0);
  float* sEw = (float*)(smem + w * 16384);
#pragma unroll
  for (int h = 0; h < 2; ++h) {
    if (h) asm volatile("s_waitcnt lgkmcnt(0)" ::: "memory");  // WAR vs h=0 reads
#pragma unroll
    for (int mi = 0; mi < 4; ++mi) {
#pragma unroll
      for (int ni = 0; ni < 4; ++ni) {
        const int colg = n0 + wn + ni*16 + lr;
        const float bvv = args.bias ? (float)args.bias[colg] : 0.0f;
#pragma unroll
        for (int rg = 0; rg < 4; ++rg) {
          const int row = mi*16 + quad*4 + rg;   // 0..63
          sEw[row*64 + ((ni*16 + lr) ^ ((row & 15)*4))] = acc[h*4 + mi][ni][rg] + bvv;
        }
      }
    }
    asm volatile("s_waitcnt lgkmcnt(0)" ::: "memory");
#pragma unroll
    for (int i = 0; i < 8; ++i) {
      const int c = i*64 + lane;
      const int row = c >> 3, ch = c & 7;
      const int d0 = ch * 8;
      const int swz = (row & 15) * 4;
      f32x4 v0 = *(const f32x4*)(sEw + row*64 + (d0 ^ swz));
      f32x4 v1 = *(const f32x4*)(sEw + row*64 + ((d0 + 4) ^ swz));
      const size_t base = (size_t)(m0 + wm + h*64 + row)*N + n0 + wn + d0;
      if (f32out) {
        *(f32x4*)((float*)args.C + base)     = v0;
        *(f32x4*)((float*)args.C + base + 4) = v1;
      } else {
        bf16x8 wv;
        wv[0]=(bf16)v0[0]; wv[1]=(bf16)v0[1]; wv[2]=(bf16)v0[2]; wv[3]=(bf16)v0[3];
        wv[4]=(bf16)v1[0]; wv[5]=(bf16)v1[1]; wv[6]=(bf16)v1[2]; wv[7]=(bf16)v1[3];
        *(bf16x8*)((bf16*)args.C + base) = wv;
      }
    }
  }
}

// xE[b,r,d] += sum_n P[n,r] * xb[b,n,dslice] (verified round 5)
__global__ __launch_bounds__(256, 4) void lowrank_xe(
    const bf16* __restrict__ E, const bf16* __restrict__ Fm,
    const bf16* __restrict__ xb,
    float* __restrict__ xEf, float* __restrict__ xFf) {
  const int bx = blockIdx.x;
  const int b = bx >> 4, dt = bx & 15;
  const int seg = blockIdx.y;
  const bf16* P = blockIdx.z ? Fm : E;
  float* O      = blockIdx.z ? xFf : xEf;

  __shared__ bf16 sP[4096];
  __shared__ bf16 sX[4096];
  const int t = threadIdx.x;
  const int r0 = (t >> 4) * 4, d0 = (t & 15) * 4;
  float acc[4][4] = {};

  for (int c8 = 0; c8 < 8; ++c8) {
    const int nb = seg*512 + c8*64;
    *(uint4*)(sP + t*8)        = *(const uint4*)(P + (size_t)nb*RV + t*8);
    *(uint4*)(sP + 2048 + t*8) = *(const uint4*)(P + (size_t)nb*RV + 2048 + t*8);
#pragma unroll
    for (int i = 0; i < 2; ++i) {
      const int c = i*256 + t;
      const int row = c >> 3, k8 = c & 7;
      *(uint4*)(sX + row*64 + k8*8) =
          *(const uint4*)(xb + ((size_t)b*NB + nb + row)*DB + dt*64 + k8*8);
    }
    __syncthreads();
#pragma unroll 16
    for (int n = 0; n < 64; ++n) {
      bf16x4 pv = *(const bf16x4*)(sP + n*64 + r0);
      bf16x4 xv = *(const bf16x4*)(sX + n*64 + d0);
      float pf[4], xf[4];
#pragma unroll
      for (int i = 0; i < 4; ++i) { pf[i] = (float)pv[i]; xf[i] = (float)xv[i]; }
#pragma unroll
      for (int i = 0; i < 4; ++i)
#pragma unroll
        for (int j = 0; j < 4; ++j)
          acc[i][j] = fmaf(pf[i], xf[j], acc[i][j]);
    }
    __syncthreads();
  }
  float* Ob = O + ((size_t)b*64)*DB + dt*64;
#pragma unroll
  for (int i = 0; i < 4; ++i)
#pragma unroll
    for (int j = 0; j < 4; ++j)
      atomicAdd(&Ob[(size_t)(r0+i)*DB + d0 + j], acc[i][j]);
}

// MFMA attention: per block one (b,h) x 128 Q-rows. S = Q.Klow^T (16x16x32
// MFMAs), softmax in-reg (16-lane shfl reduce per C-row), P via per-wave
// swizzled LDS (C-layout -> A-layout), O = P.Vlow. Klow/Vlow staged bf16.
__global__ __launch_bounds__(256, 2) void attn_mfma(
    const bf16* Q, const float* __restrict__ Klow,
    const float* __restrict__ Vlow, bf16* AO) {
  const int bh = blockIdx.x, b = bh >> 4, h = bh & 15;
  const int n0 = blockIdx.y * 128;

  __shared__ bf16 sQ[128*64];     // 16 KiB, gemm-swizzled
  __shared__ bf16 sKb[64*64];     // 8 KiB  [r][d] swizzled
  __shared__ bf16 sVt[64*64];     // 8 KiB  [d][r] swizzled (transposed)
  __shared__ bf16 sP[4][32*64];   // 16 KiB, per-wave

  const int t = threadIdx.x;
  const int lane = t & 63;
  const int w = t >> 6;
  const int lr = lane & 15;
  const int quad = lane >> 4;

  // stage Q tile: rows n0..n0+127, cols h*64..h*64+63
#pragma unroll
  for (int i = 0; i < 4; ++i) {
    const int c = i*256 + t;
    const int row = c >> 3, j = c & 7;
    const uint4 v = *(const uint4*)(Q + ((size_t)b*NB + n0 + row)*DB + h*64 + j*8);
    *(uint4*)(sQ + (row*8 + (j ^ (row & 7)))*8) = v;
  }
  // stage Klow -> sKb (bf16, [r][d] swizzled) and Vlow -> sVt ([d][r])
  {
    const int r = t >> 2, c0 = (t & 3) * 16;
    const float* kb = Klow + (size_t)(b*64 + r)*DB + h*64 + c0;
    const float* vb = Vlow + (size_t)(b*64 + r)*DB + h*64 + c0;
    float kf[16], vf[16];
#pragma unroll
    for (int i = 0; i < 4; ++i) {
      *(f32x4*)(kf + i*4) = *(const f32x4*)(kb + i*4);
      *(f32x4*)(vf + i*4) = *(const f32x4*)(vb + i*4);
    }
#pragma unroll
    for (int cc = 0; cc < 2; ++cc) {
      bf16x8 pk;
#pragma unroll
      for (int j2 = 0; j2 < 8; ++j2) pk[j2] = (bf16)kf[cc*8 + j2];
      const int ch = (c0 >> 3) + cc;
      *(bf16x8*)(sKb + (r*8 + (ch ^ (r & 7)))*8) = pk;
    }
#pragma unroll
    for (int j2 = 0; j2 < 16; ++j2) {
      const int d = c0 + j2;
      sVt[d*64 + (((r >> 3) ^ (d & 7))*8) + (r & 7)] = (bf16)vf[j2];
    }
  }
  __syncthreads();

  // S = Q . Klow^T   (per wave: 32 rows, full r=64)
  f32x4 accS[2][4] = {};
#pragma unroll
  for (int ks = 0; ks < 2; ++ks) {
    const int kc = ks*4 + quad;
    bf16x8 af[2], bv[4];
#pragma unroll
    for (int mi = 0; mi < 2; ++mi) {
      const int m = w*32 + mi*16 + lr;
      af[mi] = *(const bf16x8*)(sQ + (m*8 + (kc ^ (m & 7)))*8);
    }
#pragma unroll
    for (int ni = 0; ni < 4; ++ni) {
      const int r = ni*16 + lr;
      bv[ni] = *(const bf16x8*)(sKb + (r*8 + (kc ^ (r & 7)))*8);
    }
#pragma unroll
    for (int mi = 0; mi < 2; ++mi)
#pragma unroll
      for (int ni = 0; ni < 4; ++ni)
        accS[mi][ni] = __builtin_amdgcn_mfma_f32_16x16x32_bf16(
            af[mi], bv[ni], accS[mi][ni], 0, 0, 0);
  }

  // softmax over r (C-layout: row=quad*4+rg local, col r=ni*16+lr)
  float inv_[2][4];
#pragma unroll
  for (int mi = 0; mi < 2; ++mi)
#pragma unroll
    for (int rg = 0; rg < 4; ++rg) {
      float mv = -3.0e38f;
#pragma unroll
      for (int ni = 0; ni < 4; ++ni) mv = fmaxf(mv, accS[mi][ni][rg]);
#pragma unroll
      for (int d = 1; d < 16; d <<= 1) mv = fmaxf(mv, __shfl_xor(mv, d));
      float sum = 0.0f;
#pragma unroll
      for (int ni = 0; ni < 4; ++ni) {
        const float p = __expf((accS[mi][ni][rg] - mv) * 0.125f);
        accS[mi][ni][rg] = p;
        sum += p;
      }
#pragma unroll
      for (int d = 1; d < 16; d <<= 1) sum += __shfl_xor(sum, d);
      inv_[mi][rg] = 1.0f / sum;   // applied at O-write (PV is linear)
    }

  // P: C-layout -> A-layout via per-wave swizzled LDS (no barrier needed)
  bf16* myP = sP[w];
#pragma unroll
  for (int mi = 0; mi < 2; ++mi)
#pragma unroll
    for (int ni = 0; ni < 4; ++ni)
#pragma unroll
      for (int rg = 0; rg < 4; ++rg) {
        const int row = mi*16 + quad*4 + rg;
        const int col = ni*16 + lr;
        myP[row*64 + ((col >> 3) ^ (row & 7))*8 + (col & 7)] = (bf16)accS[mi][ni][rg];
      }

  // O = P . Vlow   (gemm-NT against sVt[d][r])
  f32x4 accO[2][4] = {};
#pragma unroll
  for (int ks = 0; ks < 2; ++ks) {
    const int kc = ks*4 + quad;
    bf16x8 ap[2], bvv[4];
#pragma unroll
    for (int mi = 0; mi < 2; ++mi) {
      const int m = mi*16 + lr;
      ap[mi] = *(const bf16x8*)(myP + (m*8 + (kc ^ (m & 7)))*8);
    }
#pragma unroll
    for (int di = 0; di < 4; ++di) {
      const int d = di*16 + lr;
      bvv[di] = *(const bf16x8*)(sVt + (d*8 + (kc ^ (d & 7)))*8);
    }
#pragma unroll
    for (int mi = 0; mi < 2; ++mi)
#pragma unroll
      for (int di = 0; di < 4; ++di)
        accO[mi][di] = __builtin_amdgcn_mfma_f32_16x16x32_bf16(
            ap[mi], bvv[di], accO[mi][di], 0, 0, 0);
  }

  // write O: re-stage through the per-wave LDS patch (overwriting P, which
  // the PV MFMAs have fully consumed), then 16-B vectorized global stores.
  // (AO may alias Q: all global Q reads happened before the barrier.)
#pragma unroll
  for (int mi = 0; mi < 2; ++mi)
#pragma unroll
    for (int di = 0; di < 4; ++di)
#pragma unroll
      for (int rg = 0; rg < 4; ++rg) {
        const int row = mi*16 + quad*4 + rg;     // 0..31
        const int col = di*16 + lr;              // 0..63
        myP[row*64 + ((col >> 3) ^ (row & 7))*8 + (col & 7)] =
            (bf16)(accO[mi][di][rg] * inv_[mi][rg]);
      }
  asm volatile("s_waitcnt lgkmcnt(0)" ::: "memory");
#pragma unroll
  for (int i = 0; i < 4; ++i) {
    const int c = i*64 + lane;
    const int row = c >> 3, ch = c & 7;
    const bf16x8 v = *(const bf16x8*)(myP + row*64 + ((ch ^ (row & 7))*8));
    *(bf16x8*)(AO + ((size_t)b*NB + n0 + w*32 + row)*DB + h*64 + ch*8) = v;
  }
}

extern "C" void kernel_launch(void* const* d_in, const int* in_sizes, int n_in,
                              void* d_out, int out_size, void* d_ws, size_t ws_size,
                              hipStream_t stream) {
  char* ws = (char*)d_ws;
  const size_t MiB = 1024*1024;
  int*   flag = (int*)ws;
  float* Klow = (float*)(ws + 1*MiB);
  float* Vlow = (float*)(ws + 2*MiB);
  float* xEf  = (float*)(ws + 3*MiB);
  float* xFf  = (float*)(ws + 4*MiB);
  bf16*  xEb  = (bf16*)(ws + 5*MiB);
  bf16*  xFb  = (bf16*)(ws + 5*MiB + 512*1024);
  bf16*  Wqb  = (bf16*)(ws + 7*MiB);
  bf16*  Wkb  = (bf16*)(ws + 9*MiB);
  bf16*  Wvb  = (bf16*)(ws + 11*MiB);
  bf16*  Wob  = (bf16*)(ws + 13*MiB);
  bf16*  bob  = (bf16*)(ws + 15*MiB);
  bf16*  Eb   = (bf16*)(ws + 16*MiB);
  bf16*  Fmb  = (bf16*)(ws + 17*MiB);
  bf16*  xb   = (bf16*)(ws + 20*MiB);
  bf16*  S0   = (bf16*)(ws + 52*MiB);

  detect_dtype<<<1, 256, 0, stream>>>((const unsigned short*)d_in[0], flag);

  CvtArgs ca;
  bf16* dsts[8] = {xb, Wqb, Wkb, Wvb, Wob, bob, Eb, Fmb};
  int   ns[8]   = {16777216, 1048576, 1048576, 1048576, 1048576, 1024, 262144, 262144};
  int off = 0;
  for (int i = 0; i < 8; ++i) {
    ca.src[i] = d_in[i]; ca.dst[i] = dsts[i]; ca.n[i] = ns[i];
    ca.off[i] = off; off += (ns[i] + 2047) / 2048;
  }
  ca.off[8] = off;
  to_bf16_multi<<<dim3(off), 256, 0, stream>>>(ca, flag);

  zero_f4<<<dim3(512), 256, 0, stream>>>(xEf);   // zeros xEf+xFf

  lowrank_xe<<<dim3(64, 8, 2), 256, 0, stream>>>(Eb, Fmb, xb, xEf, xFf);
  cvt_f32_bf16<<<dim3(256), 256, 0, stream>>>(xEf, xEb, 524288);  // xEf+xFf

  GemmArgs ka;                       // Klow = xE @ Wk^T ; Vlow = xF @ Wv^T
  ka.A = xEb; ka.B = Wkb; ka.C = Klow; ka.bias = nullptr;
  ka.oflag = nullptr; ka.force_f32 = 1;
  ka.M = 256; ka.N = DB; ka.K = DB;
  gemm_nt<<<dim3(4, 1), 512, 0, stream>>>(ka);
  ka.A = xFb; ka.B = Wvb; ka.C = Vlow;
  gemm_nt<<<dim3(4, 1), 512, 0, stream>>>(ka);

  GemmArgs qa;                       // Q = x @ Wq^T
  qa.A = xb; qa.B = Wqb; qa.C = S0; qa.bias = nullptr;
  qa.oflag = nullptr; qa.force_f32 = 0;
  qa.M = MB; qa.N = DB; qa.K = DB;
  gemm_nt<<<dim3(4, 64), 512, 0, stream>>>(qa);

  attn_mfma<<<dim3(64, 32), 256, 0, stream>>>(S0, Klow, Vlow, S0);

  GemmArgs oa;                       // out = AO @ Wo^T + bo
  oa.A = S0; oa.B = Wob; oa.C = d_out; oa.bias = bob;
  oa.oflag = flag; oa.force_f32 = 0;
  oa.M = MB; oa.N = DB; oa.K = DB;
  gemm_nt<<<dim3(4, 64), 512, 0, stream>>>(oa);
}

// Round 2
// 428.829 us; speedup vs baseline: 1.8025x; 1.1768x over previous
//
#include <hip/hip_runtime.h>
#include <stdint.h>

typedef __bf16 bf16;
typedef __bf16 bf16x8 __attribute__((ext_vector_type(8)));
typedef __bf16 bf16x4 __attribute__((ext_vector_type(4)));
typedef float  f32x4  __attribute__((ext_vector_type(4)));

#define NB   4096   // sequence length
#define DB   1024   // model dim
#define RV   64     // low rank
#define MB   16384  // B*N

// ---- dtype detection (verified working, rounds 4-5) ----
__global__ void detect_dtype(const unsigned short* x, int* flag) {
  __shared__ int cnt;
  if (threadIdx.x == 0) cnt = 0;
  __syncthreads();
  int local = 0;
  for (int i = threadIdx.x; i < 8192; i += 256) {
    const int e = (x[i] >> 7) & 0xFF;
    if (e >= 0xC0) local++;
  }
  atomicAdd(&cnt, local);
  __syncthreads();
  if (threadIdx.x == 0) *flag = (cnt > 64) ? 1 : 0;  // 1 => inputs are f32
}

// ---- one dispatch converts the 6 big input tensors (E/F handled by ef_transpose) ----
struct CvtArgs {
  const void* src[8];
  bf16* dst[8];
  int n[8];
  int off[9];   // block-range prefix sums
};
__global__ void to_bf16_multi(CvtArgs a, const int* __restrict__ flag) {
  const int blk = blockIdx.x;
  int seg = 0;
#pragma unroll
  for (int s = 1; s < 8; ++s) seg += (blk >= a.off[s]);
  const int i = (blk - a.off[seg]) * 2048 + threadIdx.x * 8;
  if (i >= a.n[seg]) return;
  bf16* dst = a.dst[seg];
  if (*flag) {
    const float* s = (const float*)a.src[seg] + i;
    f32x4 x0 = *(const f32x4*)s;
    f32x4 x1 = *(const f32x4*)(s + 4);
    bf16x8 v;
    v[0]=(bf16)x0[0]; v[1]=(bf16)x0[1]; v[2]=(bf16)x0[2]; v[3]=(bf16)x0[3];
    v[4]=(bf16)x1[0]; v[5]=(bf16)x1[1]; v[6]=(bf16)x1[2]; v[7]=(bf16)x1[3];
    *(bf16x8*)(dst + i) = v;
  } else {
    *(uint4*)(dst + i) = *(const uint4*)((const bf16*)a.src[seg] + i);
  }
}

// EFt[m][n] = (m<64 ? E : F)[n][m&63]  -- 128x4096 bf16, built once (1 MB).
// Column reads are uncoalesced but the 2 MB source lives in L2/L3.
__global__ __launch_bounds__(256) void ef_transpose(
    const void* __restrict__ E, const void* __restrict__ F,
    bf16* __restrict__ EFt, const int* __restrict__ flag) {
  const int m = blockIdx.x;           // 0..127
  const int z = m >> 6, r = m & 63;
  const void* src = z ? F : E;
  const int t = threadIdx.x;
  bf16* dst = EFt + (size_t)m * 4096;
  if (*flag) {
    const float* s = (const float*)src;
#pragma unroll
    for (int i = 0; i < 16; ++i) {
      const int n = i*256 + t;
      dst[n] = (bf16)s[(size_t)n*RV + r];
    }
  } else {
    const bf16* s = (const bf16*)src;
#pragma unroll
    for (int i = 0; i < 16; ++i) {
      const int n = i*256 + t;
      dst[n] = s[(size_t)n*RV + r];
    }
  }
}

// async global->LDS, 16B per lane, wave-uniform LDS base
typedef __attribute__((address_space(1))) const void g_as1_void;
typedef __attribute__((address_space(3))) void as3_void;
static __device__ __forceinline__ void gload16(const void* g, void* l) {
  __builtin_amdgcn_global_load_lds((g_as1_void*)g, (as3_void*)l, 16, 0, 0);
}

// xEb[b][r][d] = bf16( sum_n E[n,r]*x[b,n,d] ), xFb likewise, via MFMA.
// Grid (4 b, 32 d-tiles of 32); full K=4096 per block -> no atomics.
// A = EFt rows (k-contiguous, gload_lds staged, double-buffered);
// B = x^T built per 64-k tile by scalar LDS transpose (conflict-free:
// each write instr lands 64 lanes on 64 contiguous elems = 2/bank).
// Wave w: m-half (w&1)*64 (4 frags), d-quarter (w>>1)*16 (1 frag).
__global__ __launch_bounds__(256, 4) void lowrank_mfma(
    const bf16* __restrict__ EFt, const bf16* __restrict__ xb,
    bf16* __restrict__ xEb, bf16* __restrict__ xFb) {
  const int b = blockIdx.x, dt = blockIdx.y;
  __shared__ __align__(16) bf16 sEF0[128*64];   // 16 KiB
  __shared__ __align__(16) bf16 sEF1[128*64];   // 16 KiB
  __shared__ __align__(16) bf16 sXT[32*64];     // 4 KiB  [d][k] swizzled
  const int t = threadIdx.x, lane = t & 63, w = t >> 6;
  const int lr = lane & 15, quad = lane >> 4;
  const int wm = (w & 1) * 64, wd = (w >> 1) * 16;

  // A staging: chunk c = i*256+t -> row=c>>3, ch=c&7; src col-chunk = ch^(row&7)
  const bf16* gA[4];
  int abase[4];                      // wave-uniform LDS base (elements)
#pragma unroll
  for (int i = 0; i < 4; ++i) {
    const int c = i*256 + t, row = c >> 3, ch = c & 7;
    gA[i] = EFt + (size_t)row*4096 + (ch ^ (row & 7))*8;
    abase[i] = (i*256 + (w << 6)) * 8;
  }
  // x: thread owns row k0+lane, d-slice w*8..w*8+7 (one uint4 per k-tile)
  const bf16* gx = xb + ((size_t)b*NB + lane)*DB + dt*32 + w*8;
  int xslot[8];
#pragma unroll
  for (int j = 0; j < 8; ++j) {
    const int d = w*8 + j;
    xslot[j] = (d*8 + ((lane >> 3) ^ (d & 7)))*8 + (lane & 7);
  }
  f32x4 acc[4] = {};

  uint4 rx = *(const uint4*)gx;
#pragma unroll
  for (int i = 0; i < 4; ++i) gload16(gA[i], sEF0 + abase[i]);
  asm volatile("s_waitcnt vmcnt(0)" ::: "memory");
  __syncthreads();

  for (int kt = 0; kt < 4096; kt += 64) {
    {
      const bf16* px = (const bf16*)&rx;
#pragma unroll
      for (int j = 0; j < 8; ++j) sXT[xslot[j]] = px[j];
    }
    bf16* nbuf = ((kt >> 6) & 1) ? sEF0 : sEF1;   // buffer for kt+64
    if (kt + 64 < 4096) {
#pragma unroll
      for (int i = 0; i < 4; ++i) gload16(gA[i] + kt + 64, nbuf + abase[i]);
      rx = *(const uint4*)(gx + (size_t)(kt + 64)*DB);
    }
    asm volatile("s_waitcnt lgkmcnt(0)" ::: "memory");
    __syncthreads();
    const bf16* cbuf = ((kt >> 6) & 1) ? sEF1 : sEF0;
#pragma unroll
    for (int ks = 0; ks < 2; ++ks) {
      const int kc = ks*4 + quad;
      const int dd = wd + lr;
      bf16x8 bv = *(const bf16x8*)(sXT + (dd*8 + (kc ^ (dd & 7)))*8);
#pragma unroll
      for (int mi = 0; mi < 4; ++mi) {
        const int m = wm + mi*16 + lr;
        bf16x8 af = *(const bf16x8*)(cbuf + (m*8 + (kc ^ (m & 7)))*8);
        acc[mi] = __builtin_amdgcn_mfma_f32_16x16x32_bf16(af, bv, acc[mi], 0, 0, 0);
      }
    }
    if (kt + 64 < 4096) asm volatile("s_waitcnt vmcnt(1)" ::: "memory");
    __syncthreads();
  }

  // C-layout: row = wm + mi*16 + quad*4 + rg (wave-uniform E/F half), col = wd+lr
  bf16* dstbase = (wm == 0) ? xEb : xFb;
#pragma unroll
  for (int mi = 0; mi < 4; ++mi) {
    const int rowl = (wm + mi*16 + quad*4) & 63;
#pragma unroll
    for (int rg = 0; rg < 4; ++rg)
      dstbase[((size_t)b*64 + rowl + rg)*DB + dt*32 + wd + lr] = (bf16)acc[mi][rg];
  }
}

struct GemmArgs {
  const bf16* A;
  const bf16* B;
  void* C;
  const bf16* bias;
  const int* oflag;    // runtime f32-out flag (nullable)
  int force_f32;
  int M, N, K;
};

// C[m,n] = sum_k A[m,k]*B[n,k] (+bias[n]); fp32 accum.
// 256x256 tile, BK=64, 512 threads (8 waves, 2m x 4n), double-buffered
// global_load_lds (dwordx4) with pre-swizzled global source + XOR-swizzled
// LDS reads (linear LDS dest, rule both-sides-or-neither).
// REQUIRES: M%256==0, N%256==0, K%128==0 (true for all launches here).
// XCD remap (big grids, gridDim.y==64): each XCD owns an exclusive
// 8-m-tile slab (A never fetched by two XCDs); B (2 MiB) L2-resident.
__global__ __launch_bounds__(512, 2) void gemm_nt(GemmArgs args) {
  const int K = args.K, N = args.N;
  __shared__ __align__(16) char smem[131072];
  bf16* const sA0 = (bf16*)smem;
  bf16* const sB0 = (bf16*)(smem + 32768);
  bf16* const sA1 = (bf16*)(smem + 65536);
  bf16* const sB1 = (bf16*)(smem + 98304);

  const int t = threadIdx.x;
  const int lane = t & 63;
  const int w = t >> 6;
  const int lr = lane & 15;
  const int quad = lane >> 4;
  const int wm = (w >> 2) * 128;   // 0 or 128
  const int wn = (w & 3) * 64;     // 0,64,128,192

  int bx = blockIdx.x, by = blockIdx.y;
  if (gridDim.y == 64) {           // big-GEMM remap: 256 blocks, 8 XCDs
    const int l = by * 4 + bx;     // dispatch order (x fastest)
    const int xcd = l & 7, s = l >> 3;   // s in [0,32)
    by = xcd * 8 + (s >> 2);       // XCD-exclusive 8-m-tile slab
    bx = s & 3;                    // n-fastest within slab
  }
  const int m0 = by * 256;
  const int n0 = bx * 256;

  // staging addressing: 4 gload16 per tensor per K-tile.
  // c = (i*8+w)*64+lane -> row=c>>3, ch=c&7; LDS linear at c*16B;
  // source col-chunk = ch ^ (row&7)  (inverse of the read-side XOR).
  const bf16* gA[4];
  const bf16* gB[4];
  int lds_off[4];                  // bf16 elements
#pragma unroll
  for (int i = 0; i < 4; ++i) {
    const int c = (i*8 + w)*64 + lane;
    const int row = c >> 3, ch = c & 7;
    const int sc = ch ^ (row & 7);
    gA[i] = args.A + (size_t)(m0 + row)*K + sc*8;
    gB[i] = args.B + (size_t)(n0 + row)*K + sc*8;
    lds_off[i] = (i*8 + w) * 512;  // 1024 B per wave-instruction
  }

  auto stage = [&](bf16* dA, bf16* dB, int kt) {
#pragma unroll
    for (int i = 0; i < 4; ++i) gload16(gA[i] + kt, dA + lds_off[i]);
#pragma unroll
    for (int i = 0; i < 4; ++i) gload16(gB[i] + kt, dB + lds_off[i]);
  };

  f32x4 acc[8][4] = {};
  auto compute = [&](const bf16* bA, const bf16* bB) {
#pragma unroll
    for (int ks = 0; ks < 2; ++ks) {
      const int kc = ks*4 + quad;
      bf16x8 af[8], bv[4];
#pragma unroll
      for (int mi = 0; mi < 8; ++mi) {
        const int m = wm + mi*16 + lr;
        af[mi] = *(const bf16x8*)(bA + (m*8 + (kc ^ (m & 7)))*8);
      }
#pragma unroll
      for (int ni = 0; ni < 4; ++ni) {
        const int n = wn + ni*16 + lr;
        bv[ni] = *(const bf16x8*)(bB + (n*8 + (kc ^ (n & 7)))*8);
      }
#pragma unroll
      for (int mi = 0; mi < 8; ++mi)
#pragma unroll
        for (int ni = 0; ni < 4; ++ni)
          acc[mi][ni] = __builtin_amdgcn_mfma_f32_16x16x32_bf16(
              af[mi], bv[ni], acc[mi][ni], 0, 0, 0);
    }
  };

  // prologue
  stage(sA0, sB0, 0);
  asm volatile("s_waitcnt vmcnt(0)" ::: "memory");
  __syncthreads();

  // minimum-2-phase: issue next-tile DMA, compute current, one drain+barrier
  for (int kt = 0; kt < K; kt += 128) {
    stage(sA1, sB1, kt + 64);
    compute(sA0, sB0);
    asm volatile("s_waitcnt vmcnt(0)" ::: "memory");
    __syncthreads();
    if (kt + 128 < K) stage(sA0, sB0, kt + 128);
    compute(sA1, sB1);
    asm volatile("s_waitcnt vmcnt(0)" ::: "memory");
    __syncthreads();
  }

  // epilogue: per-wave 16 KiB LDS patch (64x64 f32), wide 16-B stores.
  const int f32out = args.force_f32 | (args.oflag ? *args.oflag : 0);
  float* sEw = (float*)(smem + w * 16384);
#pragma unroll
  for (int h = 0; h < 2; ++h) {
    if (h) asm volatile("s_waitcnt lgkmcnt(0)" ::: "memory");  // WAR vs h=0 reads
#pragma unroll
    for (int mi = 0; mi < 4; ++mi) {
#pragma unroll
      for (int ni = 0; ni < 4; ++ni) {
        const int colg = n0 + wn + ni*16 + lr;
        const float bvv = args.bias ? (float)args.bias[colg] : 0.0f;
#pragma unroll
        for (int rg = 0; rg < 4; ++rg) {
          const int row = mi*16 + quad*4 + rg;   // 0..63
          sEw[row*64 + ((ni*16 + lr) ^ ((row & 15)*4))] = acc[h*4 + mi][ni][rg] + bvv;
        }
      }
    }
    asm volatile("s_waitcnt lgkmcnt(0)" ::: "memory");
#pragma unroll
    for (int i = 0; i < 8; ++i) {
      const int c = i*64 + lane;
      const int row = c >> 3, ch = c & 7;
      const int d0 = ch * 8;
      const int swz = (row & 15) * 4;
      f32x4 v0 = *(const f32x4*)(sEw + row*64 + (d0 ^ swz));
      f32x4 v1 = *(const f32x4*)(sEw + row*64 + ((d0 + 4) ^ swz));
      const size_t base = (size_t)(m0 + wm + h*64 + row)*N + n0 + wn + d0;
      if (f32out) {
        *(f32x4*)((float*)args.C + base)     = v0;
        *(f32x4*)((float*)args.C + base + 4) = v1;
      } else {
        bf16x8 wv;
        wv[0]=(bf16)v0[0]; wv[1]=(bf16)v0[1]; wv[2]=(bf16)v0[2]; wv[3]=(bf16)v0[3];
        wv[4]=(bf16)v1[0]; wv[5]=(bf16)v1[1]; wv[6]=(bf16)v1[2]; wv[7]=(bf16)v1[3];
        *(bf16x8*)((bf16*)args.C + base) = wv;
      }
    }
  }
}

// MFMA attention: per block one (b,h) x 128 Q-rows. S = Q.Klow^T (16x16x32
// MFMAs), softmax in-reg (16-lane shfl reduce per C-row), P via per-wave
// swizzled LDS (C-layout -> A-layout), O = P.Vlow. Klow/Vlow staged bf16.
__global__ __launch_bounds__(256, 2) void attn_mfma(
    const bf16* Q, const float* __restrict__ Klow,
    const float* __restrict__ Vlow, bf16* AO) {
  const int bh = blockIdx.x, b = bh >> 4, h = bh & 15;
  const int n0 = blockIdx.y * 128;

  __shared__ bf16 sQ[128*64];     // 16 KiB, gemm-swizzled
  __shared__ bf16 sKb[64*64];     // 8 KiB  [r][d] swizzled
  __shared__ bf16 sVt[64*64];     // 8 KiB  [d][r] swizzled (transposed)
  __shared__ bf16 sP[4][32*64];   // 16 KiB, per-wave

  const int t = threadIdx.x;
  const int lane = t & 63;
  const int w = t >> 6;
  const int lr = lane & 15;
  const int quad = lane >> 4;

  // stage Q tile: rows n0..n0+127, cols h*64..h*64+63
#pragma unroll
  for (int i = 0; i < 4; ++i) {
    const int c = i*256 + t;
    const int row = c >> 3, j = c & 7;
    const uint4 v = *(const uint4*)(Q + ((size_t)b*NB + n0 + row)*DB + h*64 + j*8);
    *(uint4*)(sQ + (row*8 + (j ^ (row & 7)))*8) = v;
  }
  // stage Klow -> sKb (bf16, [r][d] swizzled) and Vlow -> sVt ([d][r])
  {
    const int r = t >> 2, c0 = (t & 3) * 16;
    const float* kb = Klow + (size_t)(b*64 + r)*DB + h*64 + c0;
    const float* vb = Vlow + (size_t)(b*64 + r)*DB + h*64 + c0;
    float kf[16], vf[16];
#pragma unroll
    for (int i = 0; i < 4; ++i) {
      *(f32x4*)(kf + i*4) = *(const f32x4*)(kb + i*4);
      *(f32x4*)(vf + i*4) = *(const f32x4*)(vb + i*4);
    }
#pragma unroll
    for (int cc = 0; cc < 2; ++cc) {
      bf16x8 pk;
#pragma unroll
      for (int j2 = 0; j2 < 8; ++j2) pk[j2] = (bf16)kf[cc*8 + j2];
      const int ch = (c0 >> 3) + cc;
      *(bf16x8*)(sKb + (r*8 + (ch ^ (r & 7)))*8) = pk;
    }
#pragma unroll
    for (int j2 = 0; j2 < 16; ++j2) {
      const int d = c0 + j2;
      sVt[d*64 + (((r >> 3) ^ (d & 7))*8) + (r & 7)] = (bf16)vf[j2];
    }
  }
  __syncthreads();

  // S = Q . Klow^T   (per wave: 32 rows, full r=64)
  f32x4 accS[2][4] = {};
#pragma unroll
  for (int ks = 0; ks < 2; ++ks) {
    const int kc = ks*4 + quad;
    bf16x8 af[2], bv[4];
#pragma unroll
    for (int mi = 0; mi < 2; ++mi) {
      const int m = w*32 + mi*16 + lr;
      af[mi] = *(const bf16x8*)(sQ + (m*8 + (kc ^ (m & 7)))*8);
    }
#pragma unroll
    for (int ni = 0; ni < 4; ++ni) {
      const int r = ni*16 + lr;
      bv[ni] = *(const bf16x8*)(sKb + (r*8 + (kc ^ (r & 7)))*8);
    }
#pragma unroll
    for (int mi = 0; mi < 2; ++mi)
#pragma unroll
      for (int ni = 0; ni < 4; ++ni)
        accS[mi][ni] = __builtin_amdgcn_mfma_f32_16x16x32_bf16(
            af[mi], bv[ni], accS[mi][ni], 0, 0, 0);
  }

  // softmax over r (C-layout: row=quad*4+rg local, col r=ni*16+lr)
  float inv_[2][4];
#pragma unroll
  for (int mi = 0; mi < 2; ++mi)
#pragma unroll
    for (int rg = 0; rg < 4; ++rg) {
      float mv = -3.0e38f;
#pragma unroll
      for (int ni = 0; ni < 4; ++ni) mv = fmaxf(mv, accS[mi][ni][rg]);
#pragma unroll
      for (int d = 1; d < 16; d <<= 1) mv = fmaxf(mv, __shfl_xor(mv, d));
      float sum = 0.0f;
#pragma unroll
      for (int ni = 0; ni < 4; ++ni) {
        const float p = __expf((accS[mi][ni][rg] - mv) * 0.125f);
        accS[mi][ni][rg] = p;
        sum += p;
      }
#pragma unroll
      for (int d = 1; d < 16; d <<= 1) sum += __shfl_xor(sum, d);
      inv_[mi][rg] = 1.0f / sum;   // applied at O-write (PV is linear)
    }

  // P: C-layout -> A-layout via per-wave swizzled LDS (no barrier needed)
  bf16* myP = sP[w];
#pragma unroll
  for (int mi = 0; mi < 2; ++mi)
#pragma unroll
    for (int ni = 0; ni < 4; ++ni)
#pragma unroll
      for (int rg = 0; rg < 4; ++rg) {
        const int row = mi*16 + quad*4 + rg;
        const int col = ni*16 + lr;
        myP[row*64 + ((col >> 3) ^ (row & 7))*8 + (col & 7)] = (bf16)accS[mi][ni][rg];
      }

  // O = P . Vlow   (gemm-NT against sVt[d][r])
  f32x4 accO[2][4] = {};
#pragma unroll
  for (int ks = 0; ks < 2; ++ks) {
    const int kc = ks*4 + quad;
    bf16x8 ap[2], bvv[4];
#pragma unroll
    for (int mi = 0; mi < 2; ++mi) {
      const int m = mi*16 + lr;
      ap[mi] = *(const bf16x8*)(myP + (m*8 + (kc ^ (m & 7)))*8);
    }
#pragma unroll
    for (int di = 0; di < 4; ++di) {
      const int d = di*16 + lr;
      bvv[di] = *(const bf16x8*)(sVt + (d*8 + (kc ^ (d & 7)))*8);
    }
#pragma unroll
    for (int mi = 0; mi < 2; ++mi)
#pragma unroll
      for (int di = 0; di < 4; ++di)
        accO[mi][di] = __builtin_amdgcn_mfma_f32_16x16x32_bf16(
            ap[mi], bvv[di], accO[mi][di], 0, 0, 0);
  }

  // write O: re-stage through the per-wave LDS patch (overwriting P, which
  // the PV MFMAs have fully consumed), then 16-B vectorized global stores.
  // (AO may alias Q: all global Q reads happened before the barrier.)
#pragma unroll
  for (int mi = 0; mi < 2; ++mi)
#pragma unroll
    for (int di = 0; di < 4; ++di)
#pragma unroll
      for (int rg = 0; rg < 4; ++rg) {
        const int row = mi*16 + quad*4 + rg;     // 0..31
        const int col = di*16 + lr;              // 0..63
        myP[row*64 + ((col >> 3) ^ (row & 7))*8 + (col & 7)] =
            (bf16)(accO[mi][di][rg] * inv_[mi][rg]);
      }
  asm volatile("s_waitcnt lgkmcnt(0)" ::: "memory");
#pragma unroll
  for (int i = 0; i < 4; ++i) {
    const int c = i*64 + lane;
    const int row = c >> 3, ch = c & 7;
    const bf16x8 v = *(const bf16x8*)(myP + row*64 + ((ch ^ (row & 7))*8));
    *(bf16x8*)(AO + ((size_t)b*NB + n0 + w*32 + row)*DB + h*64 + ch*8) = v;
  }
}

extern "C" void kernel_launch(void* const* d_in, const int* in_sizes, int n_in,
                              void* d_out, int out_size, void* d_ws, size_t ws_size,
                              hipStream_t stream) {
  char* ws = (char*)d_ws;
  const size_t MiB = 1024*1024;
  int*   flag = (int*)ws;
  float* Klow = (float*)(ws + 1*MiB);
  float* Vlow = (float*)(ws + 2*MiB);
  bf16*  xEb  = (bf16*)(ws + 3*MiB);
  bf16*  xFb  = (bf16*)(ws + 3*MiB + 512*1024);
  bf16*  EFt  = (bf16*)(ws + 4*MiB);
  bf16*  Wqb  = (bf16*)(ws + 7*MiB);
  bf16*  Wkb  = (bf16*)(ws + 9*MiB);
  bf16*  Wvb  = (bf16*)(ws + 11*MiB);
  bf16*  Wob  = (bf16*)(ws + 13*MiB);
  bf16*  bob  = (bf16*)(ws + 15*MiB);
  bf16*  xb   = (bf16*)(ws + 20*MiB);
  bf16*  S0   = (bf16*)(ws + 52*MiB);

  detect_dtype<<<1, 256, 0, stream>>>((const unsigned short*)d_in[0], flag);

  ef_transpose<<<dim3(128), 256, 0, stream>>>(d_in[6], d_in[7], EFt, flag);

  CvtArgs ca;
  bf16* dsts[6] = {xb, Wqb, Wkb, Wvb, Wob, bob};
  int   ns[6]   = {16777216, 1048576, 1048576, 1048576, 1048576, 1024};
  int off = 0;
  for (int i = 0; i < 6; ++i) {
    ca.src[i] = d_in[i]; ca.dst[i] = dsts[i]; ca.n[i] = ns[i];
    ca.off[i] = off; off += (ns[i] + 2047) / 2048;
  }
  for (int i = 6; i < 8; ++i) {
    ca.src[i] = d_in[0]; ca.dst[i] = xb; ca.n[i] = 0; ca.off[i] = off;
  }
  ca.off[8] = off;
  to_bf16_multi<<<dim3(off), 256, 0, stream>>>(ca, flag);

  lowrank_mfma<<<dim3(4, 32), 256, 0, stream>>>(EFt, xb, xEb, xFb);

  GemmArgs ka;                       // Klow = xE @ Wk^T ; Vlow = xF @ Wv^T
  ka.A = xEb; ka.B = Wkb; ka.C = Klow; ka.bias = nullptr;
  ka.oflag = nullptr; ka.force_f32 = 1;
  ka.M = 256; ka.N = DB; ka.K = DB;
  gemm_nt<<<dim3(4, 1), 512, 0, stream>>>(ka);
  ka.A = xFb; ka.B = Wvb; ka.C = Vlow;
  gemm_nt<<<dim3(4, 1), 512, 0, stream>>>(ka);

  GemmArgs qa;                       // Q = x @ Wq^T
  qa.A = xb; qa.B = Wqb; qa.C = S0; qa.bias = nullptr;
  qa.oflag = nullptr; qa.force_f32 = 0;
  qa.M = MB; qa.N = DB; qa.K = DB;
  gemm_nt<<<dim3(4, 64), 512, 0, stream>>>(qa);

  attn_mfma<<<dim3(64, 32), 256, 0, stream>>>(S0, Klow, Vlow, S0);

  GemmArgs oa;                       // out = AO @ Wo^T + bo
  oa.A = S0; oa.B = Wob; oa.C = d_out; oa.bias = bob;
  oa.oflag = flag; oa.force_f32 = 0;
  oa.M = MB; oa.N = DB; oa.K = DB;
  gemm_nt<<<dim3(4, 64), 512, 0, stream>>>(oa);
}

// Round 3
// 334.000 us; speedup vs baseline: 2.3143x; 1.2839x over previous
//
#include <hip/hip_runtime.h>
#include <stdint.h>

typedef __bf16 bf16;
typedef __bf16 bf16x8 __attribute__((ext_vector_type(8)));
typedef __bf16 bf16x4 __attribute__((ext_vector_type(4)));
typedef float  f32x4  __attribute__((ext_vector_type(4)));

#define NB   4096   // sequence length
#define DB   1024   // model dim
#define RV   64     // low rank
#define MB   16384  // B*N

// ---- dtype detection (verified working, rounds 4-5) ----
__global__ void detect_dtype(const unsigned short* x, int* flag) {
  __shared__ int cnt;
  if (threadIdx.x == 0) cnt = 0;
  __syncthreads();
  int local = 0;
  for (int i = threadIdx.x; i < 8192; i += 256) {
    const int e = (x[i] >> 7) & 0xFF;
    if (e >= 0xC0) local++;
  }
  atomicAdd(&cnt, local);
  __syncthreads();
  if (threadIdx.x == 0) *flag = (cnt > 64) ? 1 : 0;  // 1 => inputs are f32
}

// ---- one dispatch converts the 6 big input tensors (E/F handled by ef_transpose) ----
struct CvtArgs {
  const void* src[8];
  bf16* dst[8];
  int n[8];
  int off[9];   // block-range prefix sums
};
__global__ void to_bf16_multi(CvtArgs a, const int* __restrict__ flag) {
  const int blk = blockIdx.x;
  int seg = 0;
#pragma unroll
  for (int s = 1; s < 8; ++s) seg += (blk >= a.off[s]);
  const int i = (blk - a.off[seg]) * 2048 + threadIdx.x * 8;
  if (i >= a.n[seg]) return;
  bf16* dst = a.dst[seg];
  if (*flag) {
    const float* s = (const float*)a.src[seg] + i;
    f32x4 x0 = *(const f32x4*)s;
    f32x4 x1 = *(const f32x4*)(s + 4);
    bf16x8 v;
    v[0]=(bf16)x0[0]; v[1]=(bf16)x0[1]; v[2]=(bf16)x0[2]; v[3]=(bf16)x0[3];
    v[4]=(bf16)x1[0]; v[5]=(bf16)x1[1]; v[6]=(bf16)x1[2]; v[7]=(bf16)x1[3];
    *(bf16x8*)(dst + i) = v;
  } else {
    *(uint4*)(dst + i) = *(const uint4*)((const bf16*)a.src[seg] + i);
  }
}

// EFt[m][n] = (m<64 ? E : F)[n][m&63]  -- 128x4096 bf16, built once (1 MB).
__global__ __launch_bounds__(256) void ef_transpose(
    const void* __restrict__ E, const void* __restrict__ F,
    bf16* __restrict__ EFt, const int* __restrict__ flag) {
  const int m = blockIdx.x;           // 0..127
  const int z = m >> 6, r = m & 63;
  const void* src = z ? F : E;
  const int t = threadIdx.x;
  bf16* dst = EFt + (size_t)m * 4096;
  if (*flag) {
    const float* s = (const float*)src;
#pragma unroll
    for (int i = 0; i < 16; ++i) {
      const int n = i*256 + t;
      dst[n] = (bf16)s[(size_t)n*RV + r];
    }
  } else {
    const bf16* s = (const bf16*)src;
#pragma unroll
    for (int i = 0; i < 16; ++i) {
      const int n = i*256 + t;
      dst[n] = s[(size_t)n*RV + r];
    }
  }
}

// async global->LDS, 16B per lane, wave-uniform LDS base
typedef __attribute__((address_space(1))) const void g_as1_void;
typedef __attribute__((address_space(3))) void as3_void;
static __device__ __forceinline__ void gload16(const void* g, void* l) {
  __builtin_amdgcn_global_load_lds((g_as1_void*)g, (as3_void*)l, 16, 0, 0);
}

// xEb[b][r][d] = bf16( sum_n E[n,r]*x[b,n,d] ), xFb likewise, via MFMA.
__global__ __launch_bounds__(256, 4) void lowrank_mfma(
    const bf16* __restrict__ EFt, const bf16* __restrict__ xb,
    bf16* __restrict__ xEb, bf16* __restrict__ xFb) {
  const int b = blockIdx.x, dt = blockIdx.y;
  __shared__ __align__(16) bf16 sEF0[128*64];   // 16 KiB
  __shared__ __align__(16) bf16 sEF1[128*64];   // 16 KiB
  __shared__ __align__(16) bf16 sXT[32*64];     // 4 KiB  [d][k] swizzled
  const int t = threadIdx.x, lane = t & 63, w = t >> 6;
  const int lr = lane & 15, quad = lane >> 4;
  const int wm = (w & 1) * 64, wd = (w >> 1) * 16;

  const bf16* gA[4];
  int abase[4];                      // wave-uniform LDS base (elements)
#pragma unroll
  for (int i = 0; i < 4; ++i) {
    const int c = i*256 + t, row = c >> 3, ch = c & 7;
    gA[i] = EFt + (size_t)row*4096 + (ch ^ (row & 7))*8;
    abase[i] = (i*256 + (w << 6)) * 8;
  }
  const bf16* gx = xb + ((size_t)b*NB + lane)*DB + dt*32 + w*8;
  int xslot[8];
#pragma unroll
  for (int j = 0; j < 8; ++j) {
    const int d = w*8 + j;
    xslot[j] = (d*8 + ((lane >> 3) ^ (d & 7)))*8 + (lane & 7);
  }
  f32x4 acc[4] = {};

  uint4 rx = *(const uint4*)gx;
#pragma unroll
  for (int i = 0; i < 4; ++i) gload16(gA[i], sEF0 + abase[i]);
  asm volatile("s_waitcnt vmcnt(0)" ::: "memory");
  __syncthreads();

  for (int kt = 0; kt < 4096; kt += 64) {
    {
      const bf16* px = (const bf16*)&rx;
#pragma unroll
      for (int j = 0; j < 8; ++j) sXT[xslot[j]] = px[j];
    }
    bf16* nbuf = ((kt >> 6) & 1) ? sEF0 : sEF1;   // buffer for kt+64
    if (kt + 64 < 4096) {
#pragma unroll
      for (int i = 0; i < 4; ++i) gload16(gA[i] + kt + 64, nbuf + abase[i]);
      rx = *(const uint4*)(gx + (size_t)(kt + 64)*DB);
    }
    asm volatile("s_waitcnt lgkmcnt(0)" ::: "memory");
    __syncthreads();
    const bf16* cbuf = ((kt >> 6) & 1) ? sEF1 : sEF0;
#pragma unroll
    for (int ks = 0; ks < 2; ++ks) {
      const int kc = ks*4 + quad;
      const int dd = wd + lr;
      bf16x8 bv = *(const bf16x8*)(sXT + (dd*8 + (kc ^ (dd & 7)))*8);
#pragma unroll
      for (int mi = 0; mi < 4; ++mi) {
        const int m = wm + mi*16 + lr;
        bf16x8 af = *(const bf16x8*)(cbuf + (m*8 + (kc ^ (m & 7)))*8);
        acc[mi] = __builtin_amdgcn_mfma_f32_16x16x32_bf16(af, bv, acc[mi], 0, 0, 0);
      }
    }
    if (kt + 64 < 4096) asm volatile("s_waitcnt vmcnt(1)" ::: "memory");
    __syncthreads();
  }

  bf16* dstbase = (wm == 0) ? xEb : xFb;
#pragma unroll
  for (int mi = 0; mi < 4; ++mi) {
    const int rowl = (wm + mi*16 + quad*4) & 63;
#pragma unroll
    for (int rg = 0; rg < 4; ++rg)
      dstbase[((size_t)b*64 + rowl + rg)*DB + dt*32 + wd + lr] = (bf16)acc[mi][rg];
  }
}

struct GemmArgs {
  const bf16* A;
  const bf16* B;
  void* C;
  const bf16* bias;
  const int* oflag;    // runtime f32-out flag (nullable)
  int force_f32;
  int M, N, K;
  const bf16* A2;      // dual mode: second GEMM on blockIdx.y==1
  const bf16* B2;
  void* C2;
  int dual;
};

// C[m,n] = sum_k A[m,k]*B[n,k] (+bias[n]); fp32 accum.
// 256x256 tile, BK=32, 512 threads (8 waves, 2m x 4n).
// Counted-vmcnt software pipeline: 4 rotating LDS buffers (32 KiB each),
// 3-tile lookahead. Per sub-tile: s_waitcnt vmcnt(8) guarantees the
// 4 oldest in-flight loads (= this tile's) completed (in-order vmcnt),
// barrier, ds_read frags, issue stage of tile t+3 (buffer last read two
// barriers ago -> WAR safe), setprio(1), 32 MFMA, setprio(0).
// Loads NEVER drain to 0 in the main loop (tail: 8,8,4,0).
// REQUIRES: M%256==0, N%256==0, K%128==0 (true for all launches here).
__global__ __launch_bounds__(512, 2) void gemm_nt(GemmArgs args) {
  const int K = args.K, N = args.N;
  const bf16* Aptr = args.A;
  const bf16* Bptr = args.B;
  void* Cptr = args.C;
  __shared__ __align__(16) char smem[131072];
  bf16* const sA[4] = {(bf16*)smem,           (bf16*)(smem + 32768),
                       (bf16*)(smem + 65536), (bf16*)(smem + 98304)};
  bf16* const sB[4] = {(bf16*)(smem + 16384), (bf16*)(smem + 49152),
                       (bf16*)(smem + 81920), (bf16*)(smem + 114688)};

  const int t = threadIdx.x;
  const int lane = t & 63;
  const int w = t >> 6;
  const int lr = lane & 15;
  const int quad = lane >> 4;
  const int wm = (w >> 2) * 128;   // 0 or 128
  const int wn = (w & 3) * 64;     // 0,64,128,192

  int bx = blockIdx.x, by = blockIdx.y;
  if (args.dual) {
    if (by == 1) { Aptr = args.A2; Bptr = args.B2; Cptr = args.C2; }
    by = 0;
  } else if (gridDim.y == 64) {    // big-GEMM remap: 256 blocks, 8 XCDs
    const int l = by * 4 + bx;     // dispatch order (x fastest)
    const int xcd = l & 7, s = l >> 3;
    by = xcd * 8 + (s >> 2);       // XCD-exclusive 8-m-tile slab
    bx = s & 3;
  }
  const int m0 = by * 256;
  const int n0 = bx * 256;

  // staging: 2 gload16/thread/tensor per K-tile. c = i*512+t:
  // row=c>>2, ch=c&3; src chunk = ch ^ ((row>>1)&3); LDS linear at c*16B.
  const bf16* gA[2];
  const bf16* gB[2];
  int lds_off[2];
#pragma unroll
  for (int i = 0; i < 2; ++i) {
    const int c = i*512 + t, row = c >> 2, ch = c & 3;
    const int sc = ch ^ ((row >> 1) & 3);
    gA[i] = Aptr + (size_t)(m0 + row)*K + sc*8;
    gB[i] = Bptr + (size_t)(n0 + row)*K + sc*8;
    lds_off[i] = c * 8;
  }
  auto stage = [&](bf16* dA, bf16* dB, int ko) {
#pragma unroll
    for (int i = 0; i < 2; ++i) gload16(gA[i] + ko, dA + lds_off[i]);
#pragma unroll
    for (int i = 0; i < 2; ++i) gload16(gB[i] + ko, dB + lds_off[i]);
  };

  f32x4 acc[8][4] = {};

#define GSUB(J, WS, DOSTAGE) do {                                            \
    asm volatile("s_waitcnt " WS ::: "memory");                              \
    __syncthreads();                                                         \
    bf16x8 af[8], bv[4];                                                     \
    _Pragma("unroll")                                                        \
    for (int mi = 0; mi < 8; ++mi) {                                         \
      const int m = wm + mi*16 + lr;                                         \
      af[mi] = *(const bf16x8*)(sA[J] + m*32 + ((quad ^ ((m>>1)&3))*8));     \
    }                                                                        \
    _Pragma("unroll")                                                        \
    for (int ni = 0; ni < 4; ++ni) {                                         \
      const int n = wn + ni*16 + lr;                                         \
      bv[ni] = *(const bf16x8*)(sB[J] + n*32 + ((quad ^ ((n>>1)&3))*8));     \
    }                                                                        \
    if (DOSTAGE) stage(sA[((J)+3)&3], sB[((J)+3)&3], kt + ((J)+3)*32);       \
    __builtin_amdgcn_s_setprio(1);                                           \
    _Pragma("unroll")                                                        \
    for (int mi = 0; mi < 8; ++mi)                                           \
      _Pragma("unroll")                                                      \
      for (int ni = 0; ni < 4; ++ni)                                         \
        acc[mi][ni] = __builtin_amdgcn_mfma_f32_16x16x32_bf16(               \
            af[mi], bv[ni], acc[mi][ni], 0, 0, 0);                           \
    __builtin_amdgcn_s_setprio(0);                                           \
  } while (0)

  // prologue: stage tiles 0,1,2 (issue order = tile order, 12 loads/thread)
  stage(sA[0], sB[0], 0);
  stage(sA[1], sB[1], 32);
  stage(sA[2], sB[2], 64);

  int kt = 0;
  for (; kt + 128 < K; kt += 128) {
    GSUB(0, "vmcnt(8)", 1);
    GSUB(1, "vmcnt(8)", 1);
    GSUB(2, "vmcnt(8)", 1);
    GSUB(3, "vmcnt(8)", 1);
  }
  // last macro-iter (tiles NT-4..NT-1): one final stage, then drain 8,4,0
  GSUB(0, "vmcnt(8)", 1);
  GSUB(1, "vmcnt(8)", 0);
  GSUB(2, "vmcnt(4)", 0);
  GSUB(3, "vmcnt(0)", 0);
#undef GSUB

  __syncthreads();

  // epilogue: per-wave 16 KiB LDS patch (64x64 f32), wide 16-B stores.
  const int f32out = args.force_f32 | (args.oflag ? *args.oflag : 0);
  float* sEw = (float*)(smem + w * 16384);
#pragma unroll
  for (int h = 0; h < 2; ++h) {
    if (h) asm volatile("s_waitcnt lgkmcnt(0)" ::: "memory");  // WAR vs h=0 reads
#pragma unroll
    for (int mi = 0; mi < 4; ++mi) {
#pragma unroll
      for (int ni = 0; ni < 4; ++ni) {
        const int colg = n0 + wn + ni*16 + lr;
        const float bvv = args.bias ? (float)args.bias[colg] : 0.0f;
#pragma unroll
        for (int rg = 0; rg < 4; ++rg) {
          const int row = mi*16 + quad*4 + rg;   // 0..63
          sEw[row*64 + ((ni*16 + lr) ^ ((row & 15)*4))] = acc[h*4 + mi][ni][rg] + bvv;
        }
      }
    }
    asm volatile("s_waitcnt lgkmcnt(0)" ::: "memory");
#pragma unroll
    for (int i = 0; i < 8; ++i) {
      const int c = i*64 + lane;
      const int row = c >> 3, ch = c & 7;
      const int d0 = ch * 8;
      const int swz = (row & 15) * 4;
      f32x4 v0 = *(const f32x4*)(sEw + row*64 + (d0 ^ swz));
      f32x4 v1 = *(const f32x4*)(sEw + row*64 + ((d0 + 4) ^ swz));
      const size_t base = (size_t)(m0 + wm + h*64 + row)*N + n0 + wn + d0;
      if (f32out) {
        *(f32x4*)((float*)Cptr + base)     = v0;
        *(f32x4*)((float*)Cptr + base + 4) = v1;
      } else {
        bf16x8 wv;
        wv[0]=(bf16)v0[0]; wv[1]=(bf16)v0[1]; wv[2]=(bf16)v0[2]; wv[3]=(bf16)v0[3];
        wv[4]=(bf16)v1[0]; wv[5]=(bf16)v1[1]; wv[6]=(bf16)v1[2]; wv[7]=(bf16)v1[3];
        *(bf16x8*)((bf16*)Cptr + base) = wv;
      }
    }
  }
}

// MFMA attention: per block one (b,h) x 128 Q-rows. (verified round 1)
__global__ __launch_bounds__(256, 2) void attn_mfma(
    const bf16* Q, const float* __restrict__ Klow,
    const float* __restrict__ Vlow, bf16* AO) {
  const int bh = blockIdx.x, b = bh >> 4, h = bh & 15;
  const int n0 = blockIdx.y * 128;

  __shared__ bf16 sQ[128*64];     // 16 KiB, gemm-swizzled
  __shared__ bf16 sKb[64*64];     // 8 KiB  [r][d] swizzled
  __shared__ bf16 sVt[64*64];     // 8 KiB  [d][r] swizzled (transposed)
  __shared__ bf16 sP[4][32*64];   // 16 KiB, per-wave

  const int t = threadIdx.x;
  const int lane = t & 63;
  const int w = t >> 6;
  const int lr = lane & 15;
  const int quad = lane >> 4;

#pragma unroll
  for (int i = 0; i < 4; ++i) {
    const int c = i*256 + t;
    const int row = c >> 3, j = c & 7;
    const uint4 v = *(const uint4*)(Q + ((size_t)b*NB + n0 + row)*DB + h*64 + j*8);
    *(uint4*)(sQ + (row*8 + (j ^ (row & 7)))*8) = v;
  }
  {
    const int r = t >> 2, c0 = (t & 3) * 16;
    const float* kb = Klow + (size_t)(b*64 + r)*DB + h*64 + c0;
    const float* vb = Vlow + (size_t)(b*64 + r)*DB + h*64 + c0;
    float kf[16], vf[16];
#pragma unroll
    for (int i = 0; i < 4; ++i) {
      *(f32x4*)(kf + i*4) = *(const f32x4*)(kb + i*4);
      *(f32x4*)(vf + i*4) = *(const f32x4*)(vb + i*4);
    }
#pragma unroll
    for (int cc = 0; cc < 2; ++cc) {
      bf16x8 pk;
#pragma unroll
      for (int j2 = 0; j2 < 8; ++j2) pk[j2] = (bf16)kf[cc*8 + j2];
      const int ch = (c0 >> 3) + cc;
      *(bf16x8*)(sKb + (r*8 + (ch ^ (r & 7)))*8) = pk;
    }
#pragma unroll
    for (int j2 = 0; j2 < 16; ++j2) {
      const int d = c0 + j2;
      sVt[d*64 + (((r >> 3) ^ (d & 7))*8) + (r & 7)] = (bf16)vf[j2];
    }
  }
  __syncthreads();

  f32x4 accS[2][4] = {};
#pragma unroll
  for (int ks = 0; ks < 2; ++ks) {
    const int kc = ks*4 + quad;
    bf16x8 af[2], bv[4];
#pragma unroll
    for (int mi = 0; mi < 2; ++mi) {
      const int m = w*32 + mi*16 + lr;
      af[mi] = *(const bf16x8*)(sQ + (m*8 + (kc ^ (m & 7)))*8);
    }
#pragma unroll
    for (int ni = 0; ni < 4; ++ni) {
      const int r = ni*16 + lr;
      bv[ni] = *(const bf16x8*)(sKb + (r*8 + (kc ^ (r & 7)))*8);
    }
#pragma unroll
    for (int mi = 0; mi < 2; ++mi)
#pragma unroll
      for (int ni = 0; ni < 4; ++ni)
        accS[mi][ni] = __builtin_amdgcn_mfma_f32_16x16x32_bf16(
            af[mi], bv[ni], accS[mi][ni], 0, 0, 0);
  }

  float inv_[2][4];
#pragma unroll
  for (int mi = 0; mi < 2; ++mi)
#pragma unroll
    for (int rg = 0; rg < 4; ++rg) {
      float mv = -3.0e38f;
#pragma unroll
      for (int ni = 0; ni < 4; ++ni) mv = fmaxf(mv, accS[mi][ni][rg]);
#pragma unroll
      for (int d = 1; d < 16; d <<= 1) mv = fmaxf(mv, __shfl_xor(mv, d));
      float sum = 0.0f;
#pragma unroll
      for (int ni = 0; ni < 4; ++ni) {
        const float p = __expf((accS[mi][ni][rg] - mv) * 0.125f);
        accS[mi][ni][rg] = p;
        sum += p;
      }
#pragma unroll
      for (int d = 1; d < 16; d <<= 1) sum += __shfl_xor(sum, d);
      inv_[mi][rg] = 1.0f / sum;   // applied at O-write (PV is linear)
    }

  bf16* myP = sP[w];
#pragma unroll
  for (int mi = 0; mi < 2; ++mi)
#pragma unroll
    for (int ni = 0; ni < 4; ++ni)
#pragma unroll
      for (int rg = 0; rg < 4; ++rg) {
        const int row = mi*16 + quad*4 + rg;
        const int col = ni*16 + lr;
        myP[row*64 + ((col >> 3) ^ (row & 7))*8 + (col & 7)] = (bf16)accS[mi][ni][rg];
      }

  f32x4 accO[2][4] = {};
#pragma unroll
  for (int ks = 0; ks < 2; ++ks) {
    const int kc = ks*4 + quad;
    bf16x8 ap[2], bvv[4];
#pragma unroll
    for (int mi = 0; mi < 2; ++mi) {
      const int m = mi*16 + lr;
      ap[mi] = *(const bf16x8*)(myP + (m*8 + (kc ^ (m & 7)))*8);
    }
#pragma unroll
    for (int di = 0; di < 4; ++di) {
      const int d = di*16 + lr;
      bvv[di] = *(const bf16x8*)(sVt + (d*8 + (kc ^ (d & 7)))*8);
    }
#pragma unroll
    for (int mi = 0; mi < 2; ++mi)
#pragma unroll
      for (int di = 0; di < 4; ++di)
        accO[mi][di] = __builtin_amdgcn_mfma_f32_16x16x32_bf16(
            ap[mi], bvv[di], accO[mi][di], 0, 0, 0);
  }

#pragma unroll
  for (int mi = 0; mi < 2; ++mi)
#pragma unroll
    for (int di = 0; di < 4; ++di)
#pragma unroll
      for (int rg = 0; rg < 4; ++rg) {
        const int row = mi*16 + quad*4 + rg;     // 0..31
        const int col = di*16 + lr;              // 0..63
        myP[row*64 + ((col >> 3) ^ (row & 7))*8 + (col & 7)] =
            (bf16)(accO[mi][di][rg] * inv_[mi][rg]);
      }
  asm volatile("s_waitcnt lgkmcnt(0)" ::: "memory");
#pragma unroll
  for (int i = 0; i < 4; ++i) {
    const int c = i*64 + lane;
    const int row = c >> 3, ch = c & 7;
    const bf16x8 v = *(const bf16x8*)(myP + row*64 + ((ch ^ (row & 7))*8));
    *(bf16x8*)(AO + ((size_t)b*NB + n0 + w*32 + row)*DB + h*64 + ch*8) = v;
  }
}

extern "C" void kernel_launch(void* const* d_in, const int* in_sizes, int n_in,
                              void* d_out, int out_size, void* d_ws, size_t ws_size,
                              hipStream_t stream) {
  char* ws = (char*)d_ws;
  const size_t MiB = 1024*1024;
  int*   flag = (int*)ws;
  float* Klow = (float*)(ws + 1*MiB);
  float* Vlow = (float*)(ws + 2*MiB);
  bf16*  xEb  = (bf16*)(ws + 3*MiB);
  bf16*  xFb  = (bf16*)(ws + 3*MiB + 512*1024);
  bf16*  EFt  = (bf16*)(ws + 4*MiB);
  bf16*  Wqb  = (bf16*)(ws + 7*MiB);
  bf16*  Wkb  = (bf16*)(ws + 9*MiB);
  bf16*  Wvb  = (bf16*)(ws + 11*MiB);
  bf16*  Wob  = (bf16*)(ws + 13*MiB);
  bf16*  bob  = (bf16*)(ws + 15*MiB);
  bf16*  xb   = (bf16*)(ws + 20*MiB);
  bf16*  S0   = (bf16*)(ws + 52*MiB);

  detect_dtype<<<1, 256, 0, stream>>>((const unsigned short*)d_in[0], flag);

  ef_transpose<<<dim3(128), 256, 0, stream>>>(d_in[6], d_in[7], EFt, flag);

  CvtArgs ca;
  bf16* dsts[6] = {xb, Wqb, Wkb, Wvb, Wob, bob};
  int   ns[6]   = {16777216, 1048576, 1048576, 1048576, 1048576, 1024};
  int off = 0;
  for (int i = 0; i < 6; ++i) {
    ca.src[i] = d_in[i]; ca.dst[i] = dsts[i]; ca.n[i] = ns[i];
    ca.off[i] = off; off += (ns[i] + 2047) / 2048;
  }
  for (int i = 6; i < 8; ++i) {
    ca.src[i] = d_in[0]; ca.dst[i] = xb; ca.n[i] = 0; ca.off[i] = off;
  }
  ca.off[8] = off;
  to_bf16_multi<<<dim3(off), 256, 0, stream>>>(ca, flag);

  lowrank_mfma<<<dim3(4, 32), 256, 0, stream>>>(EFt, xb, xEb, xFb);

  GemmArgs ka;                       // dual: Klow = xE @ Wk^T ; Vlow = xF @ Wv^T
  ka.A = xEb; ka.B = Wkb; ka.C = Klow;
  ka.A2 = xFb; ka.B2 = Wvb; ka.C2 = Vlow;
  ka.dual = 1;
  ka.bias = nullptr; ka.oflag = nullptr; ka.force_f32 = 1;
  ka.M = 256; ka.N = DB; ka.K = DB;
  gemm_nt<<<dim3(4, 2), 512, 0, stream>>>(ka);

  GemmArgs qa;                       // Q = x @ Wq^T
  qa.A = xb; qa.B = Wqb; qa.C = S0; qa.bias = nullptr;
  qa.oflag = nullptr; qa.force_f32 = 0;
  qa.A2 = nullptr; qa.B2 = nullptr; qa.C2 = nullptr; qa.dual = 0;
  qa.M = MB; qa.N = DB; qa.K = DB;
  gemm_nt<<<dim3(4, 64), 512, 0, stream>>>(qa);

  attn_mfma<<<dim3(64, 32), 256, 0, stream>>>(S0, Klow, Vlow, S0);

  GemmArgs oa;                       // out = AO @ Wo^T + bo
  oa.A = S0; oa.B = Wob; oa.C = d_out; oa.bias = bob;
  oa.oflag = flag; oa.force_f32 = 0;
  oa.A2 = nullptr; oa.B2 = nullptr; oa.C2 = nullptr; oa.dual = 0;
  oa.M = MB; oa.N = DB; oa.K = DB;
  gemm_nt<<<dim3(4, 64), 512, 0, stream>>>(oa);
}

// Round 4
// 304.128 us; speedup vs baseline: 2.5416x; 1.0982x over previous
//
#include <hip/hip_runtime.h>
#include <stdint.h>

typedef __bf16 bf16;
typedef __bf16 bf16x8 __attribute__((ext_vector_type(8)));
typedef __bf16 bf16x4 __attribute__((ext_vector_type(4)));
typedef float  f32x4  __attribute__((ext_vector_type(4)));

#define NB   4096   // sequence length
#define DB   1024   // model dim
#define RV   64     // low rank
#define MB   16384  // B*N
#define NSEG 8      // lowrank split-n factor

// ---- dtype detection (verified working, rounds 4-5) ----
__global__ void detect_dtype(const unsigned short* x, int* flag) {
  __shared__ int cnt;
  if (threadIdx.x == 0) cnt = 0;
  __syncthreads();
  int local = 0;
  for (int i = threadIdx.x; i < 8192; i += 256) {
    const int e = (x[i] >> 7) & 0xFF;
    if (e >= 0xC0) local++;
  }
  atomicAdd(&cnt, local);
  __syncthreads();
  if (threadIdx.x == 0) *flag = (cnt > 64) ? 1 : 0;  // 1 => inputs are f32
}

// ---- one dispatch converts the 6 big input tensors (E/F handled by ef_transpose) ----
struct CvtArgs {
  const void* src[8];
  bf16* dst[8];
  int n[8];
  int off[9];   // block-range prefix sums
};
__global__ void to_bf16_multi(CvtArgs a, const int* __restrict__ flag) {
  const int blk = blockIdx.x;
  int seg = 0;
#pragma unroll
  for (int s = 1; s < 8; ++s) seg += (blk >= a.off[s]);
  const int i = (blk - a.off[seg]) * 2048 + threadIdx.x * 8;
  if (i >= a.n[seg]) return;
  bf16* dst = a.dst[seg];
  if (*flag) {
    const float* s = (const float*)a.src[seg] + i;
    f32x4 x0 = *(const f32x4*)s;
    f32x4 x1 = *(const f32x4*)(s + 4);
    bf16x8 v;
    v[0]=(bf16)x0[0]; v[1]=(bf16)x0[1]; v[2]=(bf16)x0[2]; v[3]=(bf16)x0[3];
    v[4]=(bf16)x1[0]; v[5]=(bf16)x1[1]; v[6]=(bf16)x1[2]; v[7]=(bf16)x1[3];
    *(bf16x8*)(dst + i) = v;
  } else {
    *(uint4*)(dst + i) = *(const uint4*)((const bf16*)a.src[seg] + i);
  }
}

// EFt[m][n] = (m<64 ? E : F)[n][m&63]  -- 128x4096 bf16, built once (1 MB).
__global__ __launch_bounds__(256) void ef_transpose(
    const void* __restrict__ E, const void* __restrict__ F,
    bf16* __restrict__ EFt, const int* __restrict__ flag) {
  const int m = blockIdx.x;           // 0..127
  const int z = m >> 6, r = m & 63;
  const void* src = z ? F : E;
  const int t = threadIdx.x;
  bf16* dst = EFt + (size_t)m * 4096;
  if (*flag) {
    const float* s = (const float*)src;
#pragma unroll
    for (int i = 0; i < 16; ++i) {
      const int n = i*256 + t;
      dst[n] = (bf16)s[(size_t)n*RV + r];
    }
  } else {
    const bf16* s = (const bf16*)src;
#pragma unroll
    for (int i = 0; i < 16; ++i) {
      const int n = i*256 + t;
      dst[n] = s[(size_t)n*RV + r];
    }
  }
}

// async global->LDS, 16B per lane, wave-uniform LDS base
typedef __attribute__((address_space(1))) const void g_as1_void;
typedef __attribute__((address_space(3))) void as3_void;
static __device__ __forceinline__ void gload16(const void* g, void* l) {
  __builtin_amdgcn_global_load_lds((g_as1_void*)g, (as3_void*)l, 16, 0, 0);
}

// Partial xE/xF via MFMA, split-n: block (b, dt, seg) contracts n-rows
// [seg*512, seg*512+512) and writes f32 partials Pf[seg][b][128][1024].
// 1024 blocks -> 4 blocks/CU (vs 128 blocks = 0.5/CU before the split).
__global__ __launch_bounds__(256, 4) void lowrank_mfma(
    const bf16* __restrict__ EFt, const bf16* __restrict__ xb,
    float* __restrict__ Pf) {
  const int b = blockIdx.x, dt = blockIdx.y, seg = blockIdx.z;
  __shared__ __align__(16) bf16 sEF0[128*64];   // 16 KiB
  __shared__ __align__(16) bf16 sEF1[128*64];   // 16 KiB
  __shared__ __align__(16) bf16 sXT[32*64];     // 4 KiB  [d][k] swizzled
  const int t = threadIdx.x, lane = t & 63, w = t >> 6;
  const int lr = lane & 15, quad = lane >> 4;
  const int wm = (w & 1) * 64, wd = (w >> 1) * 16;
  const int nbase = seg * (NB / NSEG);          // 512 rows per segment

  const bf16* gA[4];
  int abase[4];                      // wave-uniform LDS base (elements)
#pragma unroll
  for (int i = 0; i < 4; ++i) {
    const int c = i*256 + t, row = c >> 3, ch = c & 7;
    gA[i] = EFt + (size_t)row*4096 + nbase + (ch ^ (row & 7))*8;
    abase[i] = (i*256 + (w << 6)) * 8;
  }
  const bf16* gx = xb + ((size_t)b*NB + nbase + lane)*DB + dt*32 + w*8;
  int xslot[8];
#pragma unroll
  for (int j = 0; j < 8; ++j) {
    const int d = w*8 + j;
    xslot[j] = (d*8 + ((lane >> 3) ^ (d & 7)))*8 + (lane & 7);
  }
  f32x4 acc[4] = {};

  uint4 rx = *(const uint4*)gx;
#pragma unroll
  for (int i = 0; i < 4; ++i) gload16(gA[i], sEF0 + abase[i]);
  asm volatile("s_waitcnt vmcnt(0)" ::: "memory");
  __syncthreads();

  for (int kt = 0; kt < NB/NSEG; kt += 64) {
    {
      const bf16* px = (const bf16*)&rx;
#pragma unroll
      for (int j = 0; j < 8; ++j) sXT[xslot[j]] = px[j];
    }
    bf16* nbuf = ((kt >> 6) & 1) ? sEF0 : sEF1;   // buffer for kt+64
    if (kt + 64 < NB/NSEG) {
#pragma unroll
      for (int i = 0; i < 4; ++i) gload16(gA[i] + kt + 64, nbuf + abase[i]);
      rx = *(const uint4*)(gx + (size_t)(kt + 64)*DB);
    }
    asm volatile("s_waitcnt lgkmcnt(0)" ::: "memory");
    __syncthreads();
    const bf16* cbuf = ((kt >> 6) & 1) ? sEF1 : sEF0;
#pragma unroll
    for (int ks = 0; ks < 2; ++ks) {
      const int kc = ks*4 + quad;
      const int dd = wd + lr;
      bf16x8 bv = *(const bf16x8*)(sXT + (dd*8 + (kc ^ (dd & 7)))*8);
#pragma unroll
      for (int mi = 0; mi < 4; ++mi) {
        const int m = wm + mi*16 + lr;
        bf16x8 af = *(const bf16x8*)(cbuf + (m*8 + (kc ^ (m & 7)))*8);
        acc[mi] = __builtin_amdgcn_mfma_f32_16x16x32_bf16(af, bv, acc[mi], 0, 0, 0);
      }
    }
    if (kt + 64 < NB/NSEG) asm volatile("s_waitcnt vmcnt(1)" ::: "memory");
    __syncthreads();
  }

  // write f32 partials: Pf[(seg*4+b)][row128][d]
  float* dst = Pf + (((size_t)seg*4 + b)*128)*DB + dt*32 + wd + lr;
#pragma unroll
  for (int mi = 0; mi < 4; ++mi) {
    const int row128 = wm + mi*16 + quad*4;
#pragma unroll
    for (int rg = 0; rg < 4; ++rg)
      dst[(size_t)(row128 + rg)*DB] = acc[mi][rg];
  }
}

// xEb/xFb = bf16( sum_seg Pf[seg] )   (131072 threads, f32x4 loads)
__global__ __launch_bounds__(256) void lowrank_reduce(
    const float* __restrict__ Pf, bf16* __restrict__ xEb, bf16* __restrict__ xFb) {
  const int idx = blockIdx.x*256 + threadIdx.x;   // 0..131071
  const int d4  = idx & 255;          // d/4  (1024/4)
  const int row = (idx >> 8) & 127;   // 0..127
  const int b   = idx >> 15;          // 0..3
  const float* p = Pf + ((size_t)b*128 + row)*DB + d4*4;
  f32x4 s = {};
#pragma unroll
  for (int seg = 0; seg < NSEG; ++seg) {
    f32x4 v = *(const f32x4*)(p + (size_t)seg*4*128*DB);
    s[0]+=v[0]; s[1]+=v[1]; s[2]+=v[2]; s[3]+=v[3];
  }
  bf16x4 o;
  o[0]=(bf16)s[0]; o[1]=(bf16)s[1]; o[2]=(bf16)s[2]; o[3]=(bf16)s[3];
  bf16* dst = (row < 64 ? xEb : xFb) + ((size_t)b*64 + (row & 63))*DB + d4*4;
  *(bf16x4*)dst = o;
}

struct GemmArgs {
  const bf16* A;
  const bf16* B;
  void* C;
  const bf16* bias;
  const int* oflag;    // runtime f32-out flag (nullable)
  int force_f32;
  int M, N, K;
  const bf16* A2;      // dual mode: second GEMM on blockIdx.y==1
  const bf16* B2;
  void* C2;
  int dual;
};

// C[m,n] = sum_k A[m,k]*B[n,k] (+bias[n]); fp32 accum.
// 256x256 tile, BK=32, 512 threads (8 waves, 2m x 4n).
// Counted-vmcnt software pipeline: 4 rotating LDS buffers (32 KiB each),
// 3-tile lookahead; loads never drain to 0 in the main loop (tail 8,4,0).
// REQUIRES: M%256==0, N%256==0, K%128==0 (true for all launches here).
__global__ __launch_bounds__(512, 2) void gemm_nt(GemmArgs args) {
  const int K = args.K, N = args.N;
  const bf16* Aptr = args.A;
  const bf16* Bptr = args.B;
  void* Cptr = args.C;
  __shared__ __align__(16) char smem[131072];
  bf16* const sA[4] = {(bf16*)smem,           (bf16*)(smem + 32768),
                       (bf16*)(smem + 65536), (bf16*)(smem + 98304)};
  bf16* const sB[4] = {(bf16*)(smem + 16384), (bf16*)(smem + 49152),
                       (bf16*)(smem + 81920), (bf16*)(smem + 114688)};

  const int t = threadIdx.x;
  const int lane = t & 63;
  const int w = t >> 6;
  const int lr = lane & 15;
  const int quad = lane >> 4;
  const int wm = (w >> 2) * 128;   // 0 or 128
  const int wn = (w & 3) * 64;     // 0,64,128,192

  int bx = blockIdx.x, by = blockIdx.y;
  if (args.dual) {
    if (by == 1) { Aptr = args.A2; Bptr = args.B2; Cptr = args.C2; }
    by = 0;
  } else if (gridDim.y == 64) {    // big-GEMM remap: 256 blocks, 8 XCDs
    const int l = by * 4 + bx;     // dispatch order (x fastest)
    const int xcd = l & 7, s = l >> 3;
    by = xcd * 8 + (s >> 2);       // XCD-exclusive 8-m-tile slab
    bx = s & 3;
  }
  const int m0 = by * 256;
  const int n0 = bx * 256;

  const bf16* gA[2];
  const bf16* gB[2];
  int lds_off[2];
#pragma unroll
  for (int i = 0; i < 2; ++i) {
    const int c = i*512 + t, row = c >> 2, ch = c & 3;
    const int sc = ch ^ ((row >> 1) & 3);
    gA[i] = Aptr + (size_t)(m0 + row)*K + sc*8;
    gB[i] = Bptr + (size_t)(n0 + row)*K + sc*8;
    lds_off[i] = c * 8;
  }
  auto stage = [&](bf16* dA, bf16* dB, int ko) {
#pragma unroll
    for (int i = 0; i < 2; ++i) gload16(gA[i] + ko, dA + lds_off[i]);
#pragma unroll
    for (int i = 0; i < 2; ++i) gload16(gB[i] + ko, dB + lds_off[i]);
  };

  f32x4 acc[8][4] = {};

#define GSUB(J, WS, DOSTAGE) do {                                            \
    asm volatile("s_waitcnt " WS ::: "memory");                              \
    __syncthreads();                                                         \
    bf16x8 af[8], bv[4];                                                     \
    _Pragma("unroll")                                                        \
    for (int mi = 0; mi < 8; ++mi) {                                         \
      const int m = wm + mi*16 + lr;                                         \
      af[mi] = *(const bf16x8*)(sA[J] + m*32 + ((quad ^ ((m>>1)&3))*8));     \
    }                                                                        \
    _Pragma("unroll")                                                        \
    for (int ni = 0; ni < 4; ++ni) {                                         \
      const int n = wn + ni*16 + lr;                                         \
      bv[ni] = *(const bf16x8*)(sB[J] + n*32 + ((quad ^ ((n>>1)&3))*8));     \
    }                                                                        \
    if (DOSTAGE) stage(sA[((J)+3)&3], sB[((J)+3)&3], kt + ((J)+3)*32);       \
    __builtin_amdgcn_s_setprio(1);                                           \
    _Pragma("unroll")                                                        \
    for (int mi = 0; mi < 8; ++mi)                                           \
      _Pragma("unroll")                                                      \
      for (int ni = 0; ni < 4; ++ni)                                         \
        acc[mi][ni] = __builtin_amdgcn_mfma_f32_16x16x32_bf16(               \
            af[mi], bv[ni], acc[mi][ni], 0, 0, 0);                           \
    __builtin_amdgcn_s_setprio(0);                                           \
  } while (0)

  // prologue: stage tiles 0,1,2 (issue order = tile order, 12 loads/thread)
  stage(sA[0], sB[0], 0);
  stage(sA[1], sB[1], 32);
  stage(sA[2], sB[2], 64);

  int kt = 0;
  for (; kt + 128 < K; kt += 128) {
    GSUB(0, "vmcnt(8)", 1);
    GSUB(1, "vmcnt(8)", 1);
    GSUB(2, "vmcnt(8)", 1);
    GSUB(3, "vmcnt(8)", 1);
  }
  // last macro-iter (tiles NT-4..NT-1): one final stage, then drain 8,4,0
  GSUB(0, "vmcnt(8)", 1);
  GSUB(1, "vmcnt(8)", 0);
  GSUB(2, "vmcnt(4)", 0);
  GSUB(3, "vmcnt(0)", 0);
#undef GSUB

  __syncthreads();

  // epilogue: per-wave 16 KiB LDS patch (64x64 f32), wide 16-B stores.
  const int f32out = args.force_f32 | (args.oflag ? *args.oflag : 0);
  float* sEw = (float*)(smem + w * 16384);
#pragma unroll
  for (int h = 0; h < 2; ++h) {
    if (h) asm volatile("s_waitcnt lgkmcnt(0)" ::: "memory");  // WAR vs h=0 reads
#pragma unroll
    for (int mi = 0; mi < 4; ++mi) {
#pragma unroll
      for (int ni = 0; ni < 4; ++ni) {
        const int colg = n0 + wn + ni*16 + lr;
        const float bvv = args.bias ? (float)args.bias[colg] : 0.0f;
#pragma unroll
        for (int rg = 0; rg < 4; ++rg) {
          const int row = mi*16 + quad*4 + rg;   // 0..63
          sEw[row*64 + ((ni*16 + lr) ^ ((row & 15)*4))] = acc[h*4 + mi][ni][rg] + bvv;
        }
      }
    }
    asm volatile("s_waitcnt lgkmcnt(0)" ::: "memory");
#pragma unroll
    for (int i = 0; i < 8; ++i) {
      const int c = i*64 + lane;
      const int row = c >> 3, ch = c & 7;
      const int d0 = ch * 8;
      const int swz = (row & 15) * 4;
      f32x4 v0 = *(const f32x4*)(sEw + row*64 + (d0 ^ swz));
      f32x4 v1 = *(const f32x4*)(sEw + row*64 + ((d0 + 4) ^ swz));
      const size_t base = (size_t)(m0 + wm + h*64 + row)*N + n0 + wn + d0;
      if (f32out) {
        *(f32x4*)((float*)Cptr + base)     = v0;
        *(f32x4*)((float*)Cptr + base + 4) = v1;
      } else {
        bf16x8 wv;
        wv[0]=(bf16)v0[0]; wv[1]=(bf16)v0[1]; wv[2]=(bf16)v0[2]; wv[3]=(bf16)v0[3];
        wv[4]=(bf16)v1[0]; wv[5]=(bf16)v1[1]; wv[6]=(bf16)v1[2]; wv[7]=(bf16)v1[3];
        *(bf16x8*)((bf16*)Cptr + base) = wv;
      }
    }
  }
}

// MFMA attention: per block one (b,h) x 128 Q-rows. (verified round 1)
__global__ __launch_bounds__(256, 2) void attn_mfma(
    const bf16* Q, const float* __restrict__ Klow,
    const float* __restrict__ Vlow, bf16* AO) {
  const int bh = blockIdx.x, b = bh >> 4, h = bh & 15;
  const int n0 = blockIdx.y * 128;

  __shared__ bf16 sQ[128*64];     // 16 KiB, gemm-swizzled
  __shared__ bf16 sKb[64*64];     // 8 KiB  [r][d] swizzled
  __shared__ bf16 sVt[64*64];     // 8 KiB  [d][r] swizzled (transposed)
  __shared__ bf16 sP[4][32*64];   // 16 KiB, per-wave

  const int t = threadIdx.x;
  const int lane = t & 63;
  const int w = t >> 6;
  const int lr = lane & 15;
  const int quad = lane >> 4;

#pragma unroll
  for (int i = 0; i < 4; ++i) {
    const int c = i*256 + t;
    const int row = c >> 3, j = c & 7;
    const uint4 v = *(const uint4*)(Q + ((size_t)b*NB + n0 + row)*DB + h*64 + j*8);
    *(uint4*)(sQ + (row*8 + (j ^ (row & 7)))*8) = v;
  }
  {
    const int r = t >> 2, c0 = (t & 3) * 16;
    const float* kb = Klow + (size_t)(b*64 + r)*DB + h*64 + c0;
    const float* vb = Vlow + (size_t)(b*64 + r)*DB + h*64 + c0;
    float kf[16], vf[16];
#pragma unroll
    for (int i = 0; i < 4; ++i) {
      *(f32x4*)(kf + i*4) = *(const f32x4*)(kb + i*4);
      *(f32x4*)(vf + i*4) = *(const f32x4*)(vb + i*4);
    }
#pragma unroll
    for (int cc = 0; cc < 2; ++cc) {
      bf16x8 pk;
#pragma unroll
      for (int j2 = 0; j2 < 8; ++j2) pk[j2] = (bf16)kf[cc*8 + j2];
      const int ch = (c0 >> 3) + cc;
      *(bf16x8*)(sKb + (r*8 + (ch ^ (r & 7)))*8) = pk;
    }
#pragma unroll
    for (int j2 = 0; j2 < 16; ++j2) {
      const int d = c0 + j2;
      sVt[d*64 + (((r >> 3) ^ (d & 7))*8) + (r & 7)] = (bf16)vf[j2];
    }
  }
  __syncthreads();

  f32x4 accS[2][4] = {};
#pragma unroll
  for (int ks = 0; ks < 2; ++ks) {
    const int kc = ks*4 + quad;
    bf16x8 af[2], bv[4];
#pragma unroll
    for (int mi = 0; mi < 2; ++mi) {
      const int m = w*32 + mi*16 + lr;
      af[mi] = *(const bf16x8*)(sQ + (m*8 + (kc ^ (m & 7)))*8);
    }
#pragma unroll
    for (int ni = 0; ni < 4; ++ni) {
      const int r = ni*16 + lr;
      bv[ni] = *(const bf16x8*)(sKb + (r*8 + (kc ^ (r & 7)))*8);
    }
#pragma unroll
    for (int mi = 0; mi < 2; ++mi)
#pragma unroll
      for (int ni = 0; ni < 4; ++ni)
        accS[mi][ni] = __builtin_amdgcn_mfma_f32_16x16x32_bf16(
            af[mi], bv[ni], accS[mi][ni], 0, 0, 0);
  }

  float inv_[2][4];
#pragma unroll
  for (int mi = 0; mi < 2; ++mi)
#pragma unroll
    for (int rg = 0; rg < 4; ++rg) {
      float mv = -3.0e38f;
#pragma unroll
      for (int ni = 0; ni < 4; ++ni) mv = fmaxf(mv, accS[mi][ni][rg]);
#pragma unroll
      for (int d = 1; d < 16; d <<= 1) mv = fmaxf(mv, __shfl_xor(mv, d));
      float sum = 0.0f;
#pragma unroll
      for (int ni = 0; ni < 4; ++ni) {
        const float p = __expf((accS[mi][ni][rg] - mv) * 0.125f);
        accS[mi][ni][rg] = p;
        sum += p;
      }
#pragma unroll
      for (int d = 1; d < 16; d <<= 1) sum += __shfl_xor(sum, d);
      inv_[mi][rg] = 1.0f / sum;   // applied at O-write (PV is linear)
    }

  bf16* myP = sP[w];
#pragma unroll
  for (int mi = 0; mi < 2; ++mi)
#pragma unroll
    for (int ni = 0; ni < 4; ++ni)
#pragma unroll
      for (int rg = 0; rg < 4; ++rg) {
        const int row = mi*16 + quad*4 + rg;
        const int col = ni*16 + lr;
        myP[row*64 + ((col >> 3) ^ (row & 7))*8 + (col & 7)] = (bf16)accS[mi][ni][rg];
      }

  f32x4 accO[2][4] = {};
#pragma unroll
  for (int ks = 0; ks < 2; ++ks) {
    const int kc = ks*4 + quad;
    bf16x8 ap[2], bvv[4];
#pragma unroll
    for (int mi = 0; mi < 2; ++mi) {
      const int m = mi*16 + lr;
      ap[mi] = *(const bf16x8*)(myP + (m*8 + (kc ^ (m & 7)))*8);
    }
#pragma unroll
    for (int di = 0; di < 4; ++di) {
      const int d = di*16 + lr;
      bvv[di] = *(const bf16x8*)(sVt + (d*8 + (kc ^ (d & 7)))*8);
    }
#pragma unroll
    for (int mi = 0; mi < 2; ++mi)
#pragma unroll
      for (int di = 0; di < 4; ++di)
        accO[mi][di] = __builtin_amdgcn_mfma_f32_16x16x32_bf16(
            ap[mi], bvv[di], accO[mi][di], 0, 0, 0);
  }

#pragma unroll
  for (int mi = 0; mi < 2; ++mi)
#pragma unroll
    for (int di = 0; di < 4; ++di)
#pragma unroll
      for (int rg = 0; rg < 4; ++rg) {
        const int row = mi*16 + quad*4 + rg;     // 0..31
        const int col = di*16 + lr;              // 0..63
        myP[row*64 + ((col >> 3) ^ (row & 7))*8 + (col & 7)] =
            (bf16)(accO[mi][di][rg] * inv_[mi][rg]);
      }
  asm volatile("s_waitcnt lgkmcnt(0)" ::: "memory");
#pragma unroll
  for (int i = 0; i < 4; ++i) {
    const int c = i*64 + lane;
    const int row = c >> 3, ch = c & 7;
    const bf16x8 v = *(const bf16x8*)(myP + row*64 + ((ch ^ (row & 7))*8));
    *(bf16x8*)(AO + ((size_t)b*NB + n0 + w*32 + row)*DB + h*64 + ch*8) = v;
  }
}

extern "C" void kernel_launch(void* const* d_in, const int* in_sizes, int n_in,
                              void* d_out, int out_size, void* d_ws, size_t ws_size,
                              hipStream_t stream) {
  char* ws = (char*)d_ws;
  const size_t MiB = 1024*1024;
  int*   flag = (int*)ws;
  float* Klow = (float*)(ws + 1*MiB);
  float* Vlow = (float*)(ws + 2*MiB);
  bf16*  xEb  = (bf16*)(ws + 3*MiB);
  bf16*  xFb  = (bf16*)(ws + 3*MiB + 512*1024);
  bf16*  EFt  = (bf16*)(ws + 4*MiB);
  bf16*  Wqb  = (bf16*)(ws + 7*MiB);
  bf16*  Wkb  = (bf16*)(ws + 9*MiB);
  bf16*  Wvb  = (bf16*)(ws + 11*MiB);
  bf16*  Wob  = (bf16*)(ws + 13*MiB);
  bf16*  bob  = (bf16*)(ws + 15*MiB);
  bf16*  xb   = (bf16*)(ws + 20*MiB);
  bf16*  S0   = (bf16*)(ws + 52*MiB);
  // Pf (16 MiB) aliases S0's region: written by lowrank_mfma, consumed by
  // lowrank_reduce, both strictly before the Q-GEMM writes S0 (one stream).
  float* Pf   = (float*)(ws + 52*MiB);

  detect_dtype<<<1, 256, 0, stream>>>((const unsigned short*)d_in[0], flag);

  ef_transpose<<<dim3(128), 256, 0, stream>>>(d_in[6], d_in[7], EFt, flag);

  CvtArgs ca;
  bf16* dsts[6] = {xb, Wqb, Wkb, Wvb, Wob, bob};
  int   ns[6]   = {16777216, 1048576, 1048576, 1048576, 1048576, 1024};
  int off = 0;
  for (int i = 0; i < 6; ++i) {
    ca.src[i] = d_in[i]; ca.dst[i] = dsts[i]; ca.n[i] = ns[i];
    ca.off[i] = off; off += (ns[i] + 2047) / 2048;
  }
  for (int i = 6; i < 8; ++i) {
    ca.src[i] = d_in[0]; ca.dst[i] = xb; ca.n[i] = 0; ca.off[i] = off;
  }
  ca.off[8] = off;
  to_bf16_multi<<<dim3(off), 256, 0, stream>>>(ca, flag);

  lowrank_mfma<<<dim3(4, 32, NSEG), 256, 0, stream>>>(EFt, xb, Pf);
  lowrank_reduce<<<dim3(512), 256, 0, stream>>>(Pf, xEb, xFb);

  GemmArgs ka;                       // dual: Klow = xE @ Wk^T ; Vlow = xF @ Wv^T
  ka.A = xEb; ka.B = Wkb; ka.C = Klow;
  ka.A2 = xFb; ka.B2 = Wvb; ka.C2 = Vlow;
  ka.dual = 1;
  ka.bias = nullptr; ka.oflag = nullptr; ka.force_f32 = 1;
  ka.M = 256; ka.N = DB; ka.K = DB;
  gemm_nt<<<dim3(4, 2), 512, 0, stream>>>(ka);

  GemmArgs qa;                       // Q = x @ Wq^T
  qa.A = xb; qa.B = Wqb; qa.C = S0; qa.bias = nullptr;
  qa.oflag = nullptr; qa.force_f32 = 0;
  qa.A2 = nullptr; qa.B2 = nullptr; qa.C2 = nullptr; qa.dual = 0;
  qa.M = MB; qa.N = DB; qa.K = DB;
  gemm_nt<<<dim3(4, 64), 512, 0, stream>>>(qa);

  attn_mfma<<<dim3(64, 32), 256, 0, stream>>>(S0, Klow, Vlow, S0);

  GemmArgs oa;                       // out = AO @ Wo^T + bo
  oa.A = S0; oa.B = Wob; oa.C = d_out; oa.bias = bob;
  oa.oflag = flag; oa.force_f32 = 0;
  oa.A2 = nullptr; oa.B2 = nullptr; oa.C2 = nullptr; oa.dual = 0;
  oa.M = MB; oa.N = DB; oa.K = DB;
  gemm_nt<<<dim3(4, 64), 512, 0, stream>>>(oa);
}

// Round 5
// 301.481 us; speedup vs baseline: 2.5639x; 1.0088x over previous
//
#include <hip/hip_runtime.h>
#include <stdint.h>

typedef __bf16 bf16;
typedef __bf16 bf16x8 __attribute__((ext_vector_type(8)));
typedef __bf16 bf16x4 __attribute__((ext_vector_type(4)));
typedef float  f32x4  __attribute__((ext_vector_type(4)));

#define NB   4096   // sequence length
#define DB   1024   // model dim
#define RV   64     // low rank
#define MB   16384  // B*N
#define NSEG 8      // lowrank split-n factor

// ---- dtype detection (verified working, rounds 4-5) ----
__global__ void detect_dtype(const unsigned short* x, int* flag) {
  __shared__ int cnt;
  if (threadIdx.x == 0) cnt = 0;
  __syncthreads();
  int local = 0;
  for (int i = threadIdx.x; i < 8192; i += 256) {
    const int e = (x[i] >> 7) & 0xFF;
    if (e >= 0xC0) local++;
  }
  atomicAdd(&cnt, local);
  __syncthreads();
  if (threadIdx.x == 0) *flag = (cnt > 64) ? 1 : 0;  // 1 => inputs are f32
}

// ---- one dispatch converts the 6 big input tensors (E/F handled by ef_transpose) ----
struct CvtArgs {
  const void* src[8];
  bf16* dst[8];
  int n[8];
  int off[9];   // block-range prefix sums
};
__global__ void to_bf16_multi(CvtArgs a, const int* __restrict__ flag) {
  const int blk = blockIdx.x;
  int seg = 0;
#pragma unroll
  for (int s = 1; s < 8; ++s) seg += (blk >= a.off[s]);
  const int i = (blk - a.off[seg]) * 2048 + threadIdx.x * 8;
  if (i >= a.n[seg]) return;
  bf16* dst = a.dst[seg];
  if (*flag) {
    const float* s = (const float*)a.src[seg] + i;
    f32x4 x0 = *(const f32x4*)s;
    f32x4 x1 = *(const f32x4*)(s + 4);
    bf16x8 v;
    v[0]=(bf16)x0[0]; v[1]=(bf16)x0[1]; v[2]=(bf16)x0[2]; v[3]=(bf16)x0[3];
    v[4]=(bf16)x1[0]; v[5]=(bf16)x1[1]; v[6]=(bf16)x1[2]; v[7]=(bf16)x1[3];
    *(bf16x8*)(dst + i) = v;
  } else {
    *(uint4*)(dst + i) = *(const uint4*)((const bf16*)a.src[seg] + i);
  }
}

// EFt[m][n] = (m<64 ? E : F)[n][m&63]  -- 128x4096 bf16, built once (1 MB).
__global__ __launch_bounds__(256) void ef_transpose(
    const void* __restrict__ E, const void* __restrict__ F,
    bf16* __restrict__ EFt, const int* __restrict__ flag) {
  const int m = blockIdx.x;           // 0..127
  const int z = m >> 6, r = m & 63;
  const void* src = z ? F : E;
  const int t = threadIdx.x;
  bf16* dst = EFt + (size_t)m * 4096;
  if (*flag) {
    const float* s = (const float*)src;
#pragma unroll
    for (int i = 0; i < 16; ++i) {
      const int n = i*256 + t;
      dst[n] = (bf16)s[(size_t)n*RV + r];
    }
  } else {
    const bf16* s = (const bf16*)src;
#pragma unroll
    for (int i = 0; i < 16; ++i) {
      const int n = i*256 + t;
      dst[n] = s[(size_t)n*RV + r];
    }
  }
}

// async global->LDS, 16B per lane, wave-uniform LDS base
typedef __attribute__((address_space(1))) const void g_as1_void;
typedef __attribute__((address_space(3))) void as3_void;
static __device__ __forceinline__ void gload16(const void* g, void* l) {
  __builtin_amdgcn_global_load_lds((g_as1_void*)g, (as3_void*)l, 16, 0, 0);
}

// Partial xE/xF via MFMA, split-n: block (b, dt, seg) contracts n-rows
// [seg*512, seg*512+512) and writes f32 partials Pf[seg][b][128][1024].
__global__ __launch_bounds__(256, 4) void lowrank_mfma(
    const bf16* __restrict__ EFt, const bf16* __restrict__ xb,
    float* __restrict__ Pf) {
  const int b = blockIdx.x, dt = blockIdx.y, seg = blockIdx.z;
  __shared__ __align__(16) bf16 sEF0[128*64];   // 16 KiB
  __shared__ __align__(16) bf16 sEF1[128*64];   // 16 KiB
  __shared__ __align__(16) bf16 sXT[32*64];     // 4 KiB  [d][k] swizzled
  const int t = threadIdx.x, lane = t & 63, w = t >> 6;
  const int lr = lane & 15, quad = lane >> 4;
  const int wm = (w & 1) * 64, wd = (w >> 1) * 16;
  const int nbase = seg * (NB / NSEG);          // 512 rows per segment

  const bf16* gA[4];
  int abase[4];                      // wave-uniform LDS base (elements)
#pragma unroll
  for (int i = 0; i < 4; ++i) {
    const int c = i*256 + t, row = c >> 3, ch = c & 7;
    gA[i] = EFt + (size_t)row*4096 + nbase + (ch ^ (row & 7))*8;
    abase[i] = (i*256 + (w << 6)) * 8;
  }
  const bf16* gx = xb + ((size_t)b*NB + nbase + lane)*DB + dt*32 + w*8;
  int xslot[8];
#pragma unroll
  for (int j = 0; j < 8; ++j) {
    const int d = w*8 + j;
    xslot[j] = (d*8 + ((lane >> 3) ^ (d & 7)))*8 + (lane & 7);
  }
  f32x4 acc[4] = {};

  uint4 rx = *(const uint4*)gx;
#pragma unroll
  for (int i = 0; i < 4; ++i) gload16(gA[i], sEF0 + abase[i]);
  asm volatile("s_waitcnt vmcnt(0)" ::: "memory");
  __syncthreads();

  for (int kt = 0; kt < NB/NSEG; kt += 64) {
    {
      const bf16* px = (const bf16*)&rx;
#pragma unroll
      for (int j = 0; j < 8; ++j) sXT[xslot[j]] = px[j];
    }
    bf16* nbuf = ((kt >> 6) & 1) ? sEF0 : sEF1;   // buffer for kt+64
    if (kt + 64 < NB/NSEG) {
#pragma unroll
      for (int i = 0; i < 4; ++i) gload16(gA[i] + kt + 64, nbuf + abase[i]);
      rx = *(const uint4*)(gx + (size_t)(kt + 64)*DB);
    }
    asm volatile("s_waitcnt lgkmcnt(0)" ::: "memory");
    __syncthreads();
    const bf16* cbuf = ((kt >> 6) & 1) ? sEF1 : sEF0;
#pragma unroll
    for (int ks = 0; ks < 2; ++ks) {
      const int kc = ks*4 + quad;
      const int dd = wd + lr;
      bf16x8 bv = *(const bf16x8*)(sXT + (dd*8 + (kc ^ (dd & 7)))*8);
#pragma unroll
      for (int mi = 0; mi < 4; ++mi) {
        const int m = wm + mi*16 + lr;
        bf16x8 af = *(const bf16x8*)(cbuf + (m*8 + (kc ^ (m & 7)))*8);
        acc[mi] = __builtin_amdgcn_mfma_f32_16x16x32_bf16(af, bv, acc[mi], 0, 0, 0);
      }
    }
    if (kt + 64 < NB/NSEG) asm volatile("s_waitcnt vmcnt(1)" ::: "memory");
    __syncthreads();
  }

  // write f32 partials: Pf[(seg*4+b)][row128][d]
  float* dst = Pf + (((size_t)seg*4 + b)*128)*DB + dt*32 + wd + lr;
#pragma unroll
  for (int mi = 0; mi < 4; ++mi) {
    const int row128 = wm + mi*16 + quad*4;
#pragma unroll
    for (int rg = 0; rg < 4; ++rg)
      dst[(size_t)(row128 + rg)*DB] = acc[mi][rg];
  }
}

// xEb/xFb = bf16( sum_seg Pf[seg] )   (131072 threads, f32x4 loads)
__global__ __launch_bounds__(256) void lowrank_reduce(
    const float* __restrict__ Pf, bf16* __restrict__ xEb, bf16* __restrict__ xFb) {
  const int idx = blockIdx.x*256 + threadIdx.x;   // 0..131071
  const int d4  = idx & 255;          // d/4  (1024/4)
  const int row = (idx >> 8) & 127;   // 0..127
  const int b   = idx >> 15;          // 0..3
  const float* p = Pf + ((size_t)b*128 + row)*DB + d4*4;
  f32x4 s = {};
#pragma unroll
  for (int seg = 0; seg < NSEG; ++seg) {
    f32x4 v = *(const f32x4*)(p + (size_t)seg*4*128*DB);
    s[0]+=v[0]; s[1]+=v[1]; s[2]+=v[2]; s[3]+=v[3];
  }
  bf16x4 o;
  o[0]=(bf16)s[0]; o[1]=(bf16)s[1]; o[2]=(bf16)s[2]; o[3]=(bf16)s[3];
  bf16* dst = (row < 64 ? xEb : xFb) + ((size_t)b*64 + (row & 63))*DB + d4*4;
  *(bf16x4*)dst = o;
}

struct GemmArgs {
  const bf16* A;
  const bf16* B;
  void* C;
  const bf16* bias;
  const int* oflag;    // runtime f32-out flag (nullable)
  int force_f32;
  int M, N, K;
  const bf16* A2;      // dual mode: second GEMM on blockIdx.y==1
  const bf16* B2;
  void* C2;
  int dual;
};

// C[m,n] = sum_k A[m,k]*B[n,k] (+bias[n]); fp32 accum.
// 256x256 tile, BK=32, 512 threads (8 waves, 2m x 4n).
// TRUE counted-vmcnt pipeline: 4 rotating LDS buffers, 3-tile lookahead,
// RAW s_barrier (no implicit vmcnt(0) drain -- __syncthreads would emit
// "s_waitcnt vmcnt(0) lgkmcnt(0)" and defeat the counting; that drain was
// the round-4 stall). Safety: per-wave in-order vmcnt(8) ensures the 4
// oldest loads (= tile J's) landed; raw barrier makes that true for ALL
// waves before any ds_read of buffer J. WAR on stage target (J+3)&3:
// its readers' ds_reads are data-flow-ordered before their MFMAs, which
// precede barrier(J). Loads never drain to 0 in the main loop (tail 8,4,0).
// REQUIRES: M%256==0, N%256==0, K%128==0 (true for all launches here).
__global__ __launch_bounds__(512, 2) void gemm_nt(GemmArgs args) {
  const int K = args.K, N = args.N;
  const bf16* Aptr = args.A;
  const bf16* Bptr = args.B;
  void* Cptr = args.C;
  __shared__ __align__(16) char smem[131072];
  bf16* const sA[4] = {(bf16*)smem,           (bf16*)(smem + 32768),
                       (bf16*)(smem + 65536), (bf16*)(smem + 98304)};
  bf16* const sB[4] = {(bf16*)(smem + 16384), (bf16*)(smem + 49152),
                       (bf16*)(smem + 81920), (bf16*)(smem + 114688)};

  const int t = threadIdx.x;
  const int lane = t & 63;
  const int w = t >> 6;
  const int lr = lane & 15;
  const int quad = lane >> 4;
  const int wm = (w >> 2) * 128;   // 0 or 128
  const int wn = (w & 3) * 64;     // 0,64,128,192

  int bx = blockIdx.x, by = blockIdx.y;
  if (args.dual) {
    if (by == 1) { Aptr = args.A2; Bptr = args.B2; Cptr = args.C2; }
    by = 0;
  } else if (gridDim.y == 64) {    // big-GEMM remap: 256 blocks, 8 XCDs
    const int l = by * 4 + bx;     // dispatch order (x fastest)
    const int xcd = l & 7, s = l >> 3;
    by = xcd * 8 + (s >> 2);       // XCD-exclusive 8-m-tile slab
    bx = s & 3;
  }
  const int m0 = by * 256;
  const int n0 = bx * 256;

  const bf16* gA[2];
  const bf16* gB[2];
  int lds_off[2];
#pragma unroll
  for (int i = 0; i < 2; ++i) {
    const int c = i*512 + t, row = c >> 2, ch = c & 3;
    const int sc = ch ^ ((row >> 1) & 3);
    gA[i] = Aptr + (size_t)(m0 + row)*K + sc*8;
    gB[i] = Bptr + (size_t)(n0 + row)*K + sc*8;
    lds_off[i] = c * 8;
  }
  auto stage = [&](bf16* dA, bf16* dB, int ko) {
#pragma unroll
    for (int i = 0; i < 2; ++i) gload16(gA[i] + ko, dA + lds_off[i]);
#pragma unroll
    for (int i = 0; i < 2; ++i) gload16(gB[i] + ko, dB + lds_off[i]);
  };

  f32x4 acc[8][4] = {};

#define GSUB(J, WS, DOSTAGE) do {                                            \
    asm volatile("s_waitcnt " WS ::: "memory");                              \
    __builtin_amdgcn_s_barrier();                                            \
    bf16x8 af[8], bv[4];                                                     \
    _Pragma("unroll")                                                        \
    for (int mi = 0; mi < 8; ++mi) {                                         \
      const int m = wm + mi*16 + lr;                                         \
      af[mi] = *(const bf16x8*)(sA[J] + m*32 + ((quad ^ ((m>>1)&3))*8));     \
    }                                                                        \
    _Pragma("unroll")                                                        \
    for (int ni = 0; ni < 4; ++ni) {                                         \
      const int n = wn + ni*16 + lr;                                         \
      bv[ni] = *(const bf16x8*)(sB[J] + n*32 + ((quad ^ ((n>>1)&3))*8));     \
    }                                                                        \
    if (DOSTAGE) stage(sA[((J)+3)&3], sB[((J)+3)&3], kt + ((J)+3)*32);       \
    __builtin_amdgcn_s_setprio(1);                                           \
    _Pragma("unroll")                                                        \
    for (int mi = 0; mi < 8; ++mi)                                           \
      _Pragma("unroll")                                                      \
      for (int ni = 0; ni < 4; ++ni)                                         \
        acc[mi][ni] = __builtin_amdgcn_mfma_f32_16x16x32_bf16(               \
            af[mi], bv[ni], acc[mi][ni], 0, 0, 0);                           \
    __builtin_amdgcn_s_setprio(0);                                           \
  } while (0)

  // prologue: stage tiles 0,1,2 (issue order = tile order, 12 loads/thread)
  stage(sA[0], sB[0], 0);
  stage(sA[1], sB[1], 32);
  stage(sA[2], sB[2], 64);

  int kt = 0;
  for (; kt + 128 < K; kt += 128) {
    GSUB(0, "vmcnt(8)", 1);
    GSUB(1, "vmcnt(8)", 1);
    GSUB(2, "vmcnt(8)", 1);
    GSUB(3, "vmcnt(8)", 1);
  }
  // last macro-iter (tiles NT-4..NT-1): one final stage, then drain 8,4,0
  GSUB(0, "vmcnt(8)", 1);
  GSUB(1, "vmcnt(8)", 0);
  GSUB(2, "vmcnt(4)", 0);
  GSUB(3, "vmcnt(0)", 0);
#undef GSUB

  __syncthreads();   // full drain once before LDS reuse in epilogue

  // epilogue: per-wave 16 KiB LDS patch (64x64 f32), wide 16-B stores.
  const int f32out = args.force_f32 | (args.oflag ? *args.oflag : 0);
  float* sEw = (float*)(smem + w * 16384);
#pragma unroll
  for (int h = 0; h < 2; ++h) {
    if (h) asm volatile("s_waitcnt lgkmcnt(0)" ::: "memory");  // WAR vs h=0 reads
#pragma unroll
    for (int mi = 0; mi < 4; ++mi) {
#pragma unroll
      for (int ni = 0; ni < 4; ++ni) {
        const int colg = n0 + wn + ni*16 + lr;
        const float bvv = args.bias ? (float)args.bias[colg] : 0.0f;
#pragma unroll
        for (int rg = 0; rg < 4; ++rg) {
          const int row = mi*16 + quad*4 + rg;   // 0..63
          sEw[row*64 + ((ni*16 + lr) ^ ((row & 15)*4))] = acc[h*4 + mi][ni][rg] + bvv;
        }
      }
    }
    asm volatile("s_waitcnt lgkmcnt(0)" ::: "memory");
#pragma unroll
    for (int i = 0; i < 8; ++i) {
      const int c = i*64 + lane;
      const int row = c >> 3, ch = c & 7;
      const int d0 = ch * 8;
      const int swz = (row & 15) * 4;
      f32x4 v0 = *(const f32x4*)(sEw + row*64 + (d0 ^ swz));
      f32x4 v1 = *(const f32x4*)(sEw + row*64 + ((d0 + 4) ^ swz));
      const size_t base = (size_t)(m0 + wm + h*64 + row)*N + n0 + wn + d0;
      if (f32out) {
        *(f32x4*)((float*)Cptr + base)     = v0;
        *(f32x4*)((float*)Cptr + base + 4) = v1;
      } else {
        bf16x8 wv;
        wv[0]=(bf16)v0[0]; wv[1]=(bf16)v0[1]; wv[2]=(bf16)v0[2]; wv[3]=(bf16)v0[3];
        wv[4]=(bf16)v1[0]; wv[5]=(bf16)v1[1]; wv[6]=(bf16)v1[2]; wv[7]=(bf16)v1[3];
        *(bf16x8*)((bf16*)Cptr + base) = wv;
      }
    }
  }
}

// MFMA attention: per block one (b,h) x 128 Q-rows. (verified round 1)
__global__ __launch_bounds__(256, 2) void attn_mfma(
    const bf16* Q, const float* __restrict__ Klow,
    const float* __restrict__ Vlow, bf16* AO) {
  const int bh = blockIdx.x, b = bh >> 4, h = bh & 15;
  const int n0 = blockIdx.y * 128;

  __shared__ bf16 sQ[128*64];     // 16 KiB, gemm-swizzled
  __shared__ bf16 sKb[64*64];     // 8 KiB  [r][d] swizzled
  __shared__ bf16 sVt[64*64];     // 8 KiB  [d][r] swizzled (transposed)
  __shared__ bf16 sP[4][32*64];   // 16 KiB, per-wave

  const int t = threadIdx.x;
  const int lane = t & 63;
  const int w = t >> 6;
  const int lr = lane & 15;
  const int quad = lane >> 4;

#pragma unroll
  for (int i = 0; i < 4; ++i) {
    const int c = i*256 + t;
    const int row = c >> 3, j = c & 7;
    const uint4 v = *(const uint4*)(Q + ((size_t)b*NB + n0 + row)*DB + h*64 + j*8);
    *(uint4*)(sQ + (row*8 + (j ^ (row & 7)))*8) = v;
  }
  {
    const int r = t >> 2, c0 = (t & 3) * 16;
    const float* kb = Klow + (size_t)(b*64 + r)*DB + h*64 + c0;
    const float* vb = Vlow + (size_t)(b*64 + r)*DB + h*64 + c0;
    float kf[16], vf[16];
#pragma unroll
    for (int i = 0; i < 4; ++i) {
      *(f32x4*)(kf + i*4) = *(const f32x4*)(kb + i*4);
      *(f32x4*)(vf + i*4) = *(const f32x4*)(vb + i*4);
    }
#pragma unroll
    for (int cc = 0; cc < 2; ++cc) {
      bf16x8 pk;
#pragma unroll
      for (int j2 = 0; j2 < 8; ++j2) pk[j2] = (bf16)kf[cc*8 + j2];
      const int ch = (c0 >> 3) + cc;
      *(bf16x8*)(sKb + (r*8 + (ch ^ (r & 7)))*8) = pk;
    }
#pragma unroll
    for (int j2 = 0; j2 < 16; ++j2) {
      const int d = c0 + j2;
      sVt[d*64 + (((r >> 3) ^ (d & 7))*8) + (r & 7)] = (bf16)vf[j2];
    }
  }
  __syncthreads();

  f32x4 accS[2][4] = {};
#pragma unroll
  for (int ks = 0; ks < 2; ++ks) {
    const int kc = ks*4 + quad;
    bf16x8 af[2], bv[4];
#pragma unroll
    for (int mi = 0; mi < 2; ++mi) {
      const int m = w*32 + mi*16 + lr;
      af[mi] = *(const bf16x8*)(sQ + (m*8 + (kc ^ (m & 7)))*8);
    }
#pragma unroll
    for (int ni = 0; ni < 4; ++ni) {
      const int r = ni*16 + lr;
      bv[ni] = *(const bf16x8*)(sKb + (r*8 + (kc ^ (r & 7)))*8);
    }
#pragma unroll
    for (int mi = 0; mi < 2; ++mi)
#pragma unroll
      for (int ni = 0; ni < 4; ++ni)
        accS[mi][ni] = __builtin_amdgcn_mfma_f32_16x16x32_bf16(
            af[mi], bv[ni], accS[mi][ni], 0, 0, 0);
  }

  float inv_[2][4];
#pragma unroll
  for (int mi = 0; mi < 2; ++mi)
#pragma unroll
    for (int rg = 0; rg < 4; ++rg) {
      float mv = -3.0e38f;
#pragma unroll
      for (int ni = 0; ni < 4; ++ni) mv = fmaxf(mv, accS[mi][ni][rg]);
#pragma unroll
      for (int d = 1; d < 16; d <<= 1) mv = fmaxf(mv, __shfl_xor(mv, d));
      float sum = 0.0f;
#pragma unroll
      for (int ni = 0; ni < 4; ++ni) {
        const float p = __expf((accS[mi][ni][rg] - mv) * 0.125f);
        accS[mi][ni][rg] = p;
        sum += p;
      }
#pragma unroll
      for (int d = 1; d < 16; d <<= 1) sum += __shfl_xor(sum, d);
      inv_[mi][rg] = 1.0f / sum;   // applied at O-write (PV is linear)
    }

  bf16* myP = sP[w];
#pragma unroll
  for (int mi = 0; mi < 2; ++mi)
#pragma unroll
    for (int ni = 0; ni < 4; ++ni)
#pragma unroll
      for (int rg = 0; rg < 4; ++rg) {
        const int row = mi*16 + quad*4 + rg;
        const int col = ni*16 + lr;
        myP[row*64 + ((col >> 3) ^ (row & 7))*8 + (col & 7)] = (bf16)accS[mi][ni][rg];
      }

  f32x4 accO[2][4] = {};
#pragma unroll
  for (int ks = 0; ks < 2; ++ks) {
    const int kc = ks*4 + quad;
    bf16x8 ap[2], bvv[4];
#pragma unroll
    for (int mi = 0; mi < 2; ++mi) {
      const int m = mi*16 + lr;
      ap[mi] = *(const bf16x8*)(myP + (m*8 + (kc ^ (m & 7)))*8);
    }
#pragma unroll
    for (int di = 0; di < 4; ++di) {
      const int d = di*16 + lr;
      bvv[di] = *(const bf16x8*)(sVt + (d*8 + (kc ^ (d & 7)))*8);
    }
#pragma unroll
    for (int mi = 0; mi < 2; ++mi)
#pragma unroll
      for (int di = 0; di < 4; ++di)
        accO[mi][di] = __builtin_amdgcn_mfma_f32_16x16x32_bf16(
            ap[mi], bvv[di], accO[mi][di], 0, 0, 0);
  }

#pragma unroll
  for (int mi = 0; mi < 2; ++mi)
#pragma unroll
    for (int di = 0; di < 4; ++di)
#pragma unroll
      for (int rg = 0; rg < 4; ++rg) {
        const int row = mi*16 + quad*4 + rg;     // 0..31
        const int col = di*16 + lr;              // 0..63
        myP[row*64 + ((col >> 3) ^ (row & 7))*8 + (col & 7)] =
            (bf16)(accO[mi][di][rg] * inv_[mi][rg]);
      }
  asm volatile("s_waitcnt lgkmcnt(0)" ::: "memory");
#pragma unroll
  for (int i = 0; i < 4; ++i) {
    const int c = i*64 + lane;
    const int row = c >> 3, ch = c & 7;
    const bf16x8 v = *(const bf16x8*)(myP + row*64 + ((ch ^ (row & 7))*8));
    *(bf16x8*)(AO + ((size_t)b*NB + n0 + w*32 + row)*DB + h*64 + ch*8) = v;
  }
}

extern "C" void kernel_launch(void* const* d_in, const int* in_sizes, int n_in,
                              void* d_out, int out_size, void* d_ws, size_t ws_size,
                              hipStream_t stream) {
  char* ws = (char*)d_ws;
  const size_t MiB = 1024*1024;
  int*   flag = (int*)ws;
  float* Klow = (float*)(ws + 1*MiB);
  float* Vlow = (float*)(ws + 2*MiB);
  bf16*  xEb  = (bf16*)(ws + 3*MiB);
  bf16*  xFb  = (bf16*)(ws + 3*MiB + 512*1024);
  bf16*  EFt  = (bf16*)(ws + 4*MiB);
  bf16*  Wqb  = (bf16*)(ws + 7*MiB);
  bf16*  Wkb  = (bf16*)(ws + 9*MiB);
  bf16*  Wvb  = (bf16*)(ws + 11*MiB);
  bf16*  Wob  = (bf16*)(ws + 13*MiB);
  bf16*  bob  = (bf16*)(ws + 15*MiB);
  bf16*  xb   = (bf16*)(ws + 20*MiB);
  bf16*  S0   = (bf16*)(ws + 52*MiB);
  // Pf (16 MiB) aliases S0's region: written by lowrank_mfma, consumed by
  // lowrank_reduce, both strictly before the Q-GEMM writes S0 (one stream).
  float* Pf   = (float*)(ws + 52*MiB);

  detect_dtype<<<1, 256, 0, stream>>>((const unsigned short*)d_in[0], flag);

  ef_transpose<<<dim3(128), 256, 0, stream>>>(d_in[6], d_in[7], EFt, flag);

  CvtArgs ca;
  bf16* dsts[6] = {xb, Wqb, Wkb, Wvb, Wob, bob};
  int   ns[6]   = {16777216, 1048576, 1048576, 1048576, 1048576, 1024};
  int off = 0;
  for (int i = 0; i < 6; ++i) {
    ca.src[i] = d_in[i]; ca.dst[i] = dsts[i]; ca.n[i] = ns[i];
    ca.off[i] = off; off += (ns[i] + 2047) / 2048;
  }
  for (int i = 6; i < 8; ++i) {
    ca.src[i] = d_in[0]; ca.dst[i] = xb; ca.n[i] = 0; ca.off[i] = off;
  }
  ca.off[8] = off;
  to_bf16_multi<<<dim3(off), 256, 0, stream>>>(ca, flag);

  lowrank_mfma<<<dim3(4, 32, NSEG), 256, 0, stream>>>(EFt, xb, Pf);
  lowrank_reduce<<<dim3(512), 256, 0, stream>>>(Pf, xEb, xFb);

  GemmArgs ka;                       // dual: Klow = xE @ Wk^T ; Vlow = xF @ Wv^T
  ka.A = xEb; ka.B = Wkb; ka.C = Klow;
  ka.A2 = xFb; ka.B2 = Wvb; ka.C2 = Vlow;
  ka.dual = 1;
  ka.bias = nullptr; ka.oflag = nullptr; ka.force_f32 = 1;
  ka.M = 256; ka.N = DB; ka.K = DB;
  gemm_nt<<<dim3(4, 2), 512, 0, stream>>>(ka);

  GemmArgs qa;                       // Q = x @ Wq^T
  qa.A = xb; qa.B = Wqb; qa.C = S0; qa.bias = nullptr;
  qa.oflag = nullptr; qa.force_f32 = 0;
  qa.A2 = nullptr; qa.B2 = nullptr; qa.C2 = nullptr; qa.dual = 0;
  qa.M = MB; qa.N = DB; qa.K = DB;
  gemm_nt<<<dim3(4, 64), 512, 0, stream>>>(qa);

  attn_mfma<<<dim3(64, 32), 256, 0, stream>>>(S0, Klow, Vlow, S0);

  GemmArgs oa;                       // out = AO @ Wo^T + bo
  oa.A = S0; oa.B = Wob; oa.C = d_out; oa.bias = bob;
  oa.oflag = flag; oa.force_f32 = 0;
  oa.A2 = nullptr; oa.B2 = nullptr; oa.C2 = nullptr; oa.dual = 0;
  oa.M = MB; oa.N = DB; oa.K = DB;
  gemm_nt<<<dim3(4, 64), 512, 0, stream>>>(oa);
}

// Round 7
// 289.019 us; speedup vs baseline: 2.6744x; 1.0431x over previous
//
#include <hip/hip_runtime.h>
#include <stdint.h>

typedef __bf16 bf16;
typedef __bf16 bf16x8 __attribute__((ext_vector_type(8)));
typedef __bf16 bf16x4 __attribute__((ext_vector_type(4)));
typedef float  f32x4  __attribute__((ext_vector_type(4)));

#define NB   4096   // sequence length
#define DB   1024   // model dim
#define RV   64     // low rank
#define MB   16384  // B*N
#define NSEG 8      // lowrank split-n factor

// ---- dtype detection (verified working, rounds 4-5) ----
__global__ void detect_dtype(const unsigned short* x, int* flag) {
  __shared__ int cnt;
  if (threadIdx.x == 0) cnt = 0;
  __syncthreads();
  int local = 0;
  for (int i = threadIdx.x; i < 8192; i += 256) {
    const int e = (x[i] >> 7) & 0xFF;
    if (e >= 0xC0) local++;
  }
  atomicAdd(&cnt, local);
  __syncthreads();
  if (threadIdx.x == 0) *flag = (cnt > 64) ? 1 : 0;  // 1 => inputs are f32
}

// ---- one dispatch converts the 6 big input tensors (E/F handled by ef_transpose) ----
struct CvtArgs {
  const void* src[8];
  bf16* dst[8];
  int n[8];
  int off[9];   // block-range prefix sums
};
__global__ void to_bf16_multi(CvtArgs a, const int* __restrict__ flag) {
  const int blk = blockIdx.x;
  int seg = 0;
#pragma unroll
  for (int s = 1; s < 8; ++s) seg += (blk >= a.off[s]);
  const int i = (blk - a.off[seg]) * 2048 + threadIdx.x * 8;
  if (i >= a.n[seg]) return;
  bf16* dst = a.dst[seg];
  if (*flag) {
    const float* s = (const float*)a.src[seg] + i;
    f32x4 x0 = *(const f32x4*)s;
    f32x4 x1 = *(const f32x4*)(s + 4);
    bf16x8 v;
    v[0]=(bf16)x0[0]; v[1]=(bf16)x0[1]; v[2]=(bf16)x0[2]; v[3]=(bf16)x0[3];
    v[4]=(bf16)x1[0]; v[5]=(bf16)x1[1]; v[6]=(bf16)x1[2]; v[7]=(bf16)x1[3];
    *(bf16x8*)(dst + i) = v;
  } else {
    *(uint4*)(dst + i) = *(const uint4*)((const bf16*)a.src[seg] + i);
  }
}

// EFt[m][n] = (m<64 ? E : F)[n][m&63]  -- 128x4096 bf16, built once (1 MB).
__global__ __launch_bounds__(256) void ef_transpose(
    const void* __restrict__ E, const void* __restrict__ F,
    bf16* __restrict__ EFt, const int* __restrict__ flag) {
  const int m = blockIdx.x;           // 0..127
  const int z = m >> 6, r = m & 63;
  const void* src = z ? F : E;
  const int t = threadIdx.x;
  bf16* dst = EFt + (size_t)m * 4096;
  if (*flag) {
    const float* s = (const float*)src;
#pragma unroll
    for (int i = 0; i < 16; ++i) {
      const int n = i*256 + t;
      dst[n] = (bf16)s[(size_t)n*RV + r];
    }
  } else {
    const bf16* s = (const bf16*)src;
#pragma unroll
    for (int i = 0; i < 16; ++i) {
      const int n = i*256 + t;
      dst[n] = s[(size_t)n*RV + r];
    }
  }
}

// async global->LDS, 16B per lane, wave-uniform LDS base
typedef __attribute__((address_space(1))) const void g_as1_void;
typedef __attribute__((address_space(3))) void as3_void;
static __device__ __forceinline__ void gload16(const void* g, void* l) {
  __builtin_amdgcn_global_load_lds((g_as1_void*)g, (as3_void*)l, 16, 0, 0);
}

// Partial xE/xF via MFMA, split-n: block (b, dt, seg) contracts n-rows
// [seg*512, seg*512+512) and writes f32 partials Pf[seg][b][128][1024].
__global__ __launch_bounds__(256, 4) void lowrank_mfma(
    const bf16* __restrict__ EFt, const bf16* __restrict__ xb,
    float* __restrict__ Pf) {
  const int b = blockIdx.x, dt = blockIdx.y, seg = blockIdx.z;
  __shared__ __align__(16) bf16 sEF0[128*64];   // 16 KiB
  __shared__ __align__(16) bf16 sEF1[128*64];   // 16 KiB
  __shared__ __align__(16) bf16 sXT[32*64];     // 4 KiB  [d][k] swizzled
  const int t = threadIdx.x, lane = t & 63, w = t >> 6;
  const int lr = lane & 15, quad = lane >> 4;
  const int wm = (w & 1) * 64, wd = (w >> 1) * 16;
  const int nbase = seg * (NB / NSEG);          // 512 rows per segment

  const bf16* gA[4];
  int abase[4];                      // wave-uniform LDS base (elements)
#pragma unroll
  for (int i = 0; i < 4; ++i) {
    const int c = i*256 + t, row = c >> 3, ch = c & 7;
    gA[i] = EFt + (size_t)row*4096 + nbase + (ch ^ (row & 7))*8;
    abase[i] = (i*256 + (w << 6)) * 8;
  }
  const bf16* gx = xb + ((size_t)b*NB + nbase + lane)*DB + dt*32 + w*8;
  int xslot[8];
#pragma unroll
  for (int j = 0; j < 8; ++j) {
    const int d = w*8 + j;
    xslot[j] = (d*8 + ((lane >> 3) ^ (d & 7)))*8 + (lane & 7);
  }
  f32x4 acc[4] = {};

  uint4 rx = *(const uint4*)gx;
#pragma unroll
  for (int i = 0; i < 4; ++i) gload16(gA[i], sEF0 + abase[i]);
  asm volatile("s_waitcnt vmcnt(0)" ::: "memory");
  __syncthreads();

  for (int kt = 0; kt < NB/NSEG; kt += 64) {
    {
      const bf16* px = (const bf16*)&rx;
#pragma unroll
      for (int j = 0; j < 8; ++j) sXT[xslot[j]] = px[j];
    }
    bf16* nbuf = ((kt >> 6) & 1) ? sEF0 : sEF1;   // buffer for kt+64
    if (kt + 64 < NB/NSEG) {
#pragma unroll
      for (int i = 0; i < 4; ++i) gload16(gA[i] + kt + 64, nbuf + abase[i]);
      rx = *(const uint4*)(gx + (size_t)(kt + 64)*DB);
    }
    asm volatile("s_waitcnt lgkmcnt(0)" ::: "memory");
    __syncthreads();
    const bf16* cbuf = ((kt >> 6) & 1) ? sEF1 : sEF0;
#pragma unroll
    for (int ks = 0; ks < 2; ++ks) {
      const int kc = ks*4 + quad;
      const int dd = wd + lr;
      bf16x8 bv = *(const bf16x8*)(sXT + (dd*8 + (kc ^ (dd & 7)))*8);
#pragma unroll
      for (int mi = 0; mi < 4; ++mi) {
        const int m = wm + mi*16 + lr;
        bf16x8 af = *(const bf16x8*)(cbuf + (m*8 + (kc ^ (m & 7)))*8);
        acc[mi] = __builtin_amdgcn_mfma_f32_16x16x32_bf16(af, bv, acc[mi], 0, 0, 0);
      }
    }
    if (kt + 64 < NB/NSEG) asm volatile("s_waitcnt vmcnt(1)" ::: "memory");
    __syncthreads();
  }

  // write f32 partials: Pf[(seg*4+b)][row128][d]
  float* dst = Pf + (((size_t)seg*4 + b)*128)*DB + dt*32 + wd + lr;
#pragma unroll
  for (int mi = 0; mi < 4; ++mi) {
    const int row128 = wm + mi*16 + quad*4;
#pragma unroll
    for (int rg = 0; rg < 4; ++rg)
      dst[(size_t)(row128 + rg)*DB] = acc[mi][rg];
  }
}

// xEb/xFb = bf16( sum_seg Pf[seg] )   (131072 threads, f32x4 loads)
__global__ __launch_bounds__(256) void lowrank_reduce(
    const float* __restrict__ Pf, bf16* __restrict__ xEb, bf16* __restrict__ xFb) {
  const int idx = blockIdx.x*256 + threadIdx.x;   // 0..131071
  const int d4  = idx & 255;          // d/4  (1024/4)
  const int row = (idx >> 8) & 127;   // 0..127
  const int b   = idx >> 15;          // 0..3
  const float* p = Pf + ((size_t)b*128 + row)*DB + d4*4;
  f32x4 s = {};
#pragma unroll
  for (int seg = 0; seg < NSEG; ++seg) {
    f32x4 v = *(const f32x4*)(p + (size_t)seg*4*128*DB);
    s[0]+=v[0]; s[1]+=v[1]; s[2]+=v[2]; s[3]+=v[3];
  }
  bf16x4 o;
  o[0]=(bf16)s[0]; o[1]=(bf16)s[1]; o[2]=(bf16)s[2]; o[3]=(bf16)s[3];
  bf16* dst = (row < 64 ? xEb : xFb) + ((size_t)b*64 + (row & 63))*DB + d4*4;
  *(bf16x4*)dst = o;
}

struct GemmArgs {
  const bf16* A;
  const bf16* B;
  void* C;
  const bf16* bias;
  const int* oflag;    // runtime f32-out flag (nullable)
  int force_f32;
  int M, N, K;
  const bf16* A2;      // dual mode: second GEMM on blockIdx.z==1
  const bf16* B2;
  void* C2;
  int dual;
};

// C[m,n] = sum_k A[m,k]*B[n,k] (+bias[n]); fp32 accum.
// m97-structure: 128x128 tile, BK=64, 256 threads (4 waves, 2m x 2n),
// 32 KiB single-buffer LDS, plain drain loop. Throughput comes from
// inter-block TLP: __launch_bounds__(256,4) caps VGPR at 128 so 4 blocks
// co-reside per CU (LDS allows 5) -- one block's barrier/drain stall
// overlaps another block's MFMA (m114 mechanism; m97 measured 874-912 TF
// with this exact shape). Rounds 4-5 proved intra-block scheduling at
// 1 block/CU is a dead end (47->51 us).
// REQUIRES: M%128==0, N%128==0, K%64==0 (true for all launches here).
// XCD remap (big grids, gridDim.y==128): each XCD owns a 16-m-tile slab.
__global__ __launch_bounds__(256, 4) void gemm_nt(GemmArgs args) {
  const int K = args.K, N = args.N;
  const bf16* Aptr = args.A;
  const bf16* Bptr = args.B;
  void* Cptr = args.C;
  if (args.dual && blockIdx.z == 1) { Aptr = args.A2; Bptr = args.B2; Cptr = args.C2; }
  __shared__ __align__(16) char smem[32768];
  bf16* const sA = (bf16*)smem;
  bf16* const sB = (bf16*)(smem + 16384);

  const int t = threadIdx.x;
  const int lane = t & 63;
  const int w = t >> 6;
  const int lr = lane & 15;
  const int quad = lane >> 4;
  const int wm = (w & 1) * 64;     // 0 or 64
  const int wn = (w >> 1) * 64;    // 0 or 64

  int bx = blockIdx.x, by = blockIdx.y;
  if (gridDim.y == 128) {          // big-GEMM remap: 1024 blocks, 8 XCDs
    const int l = by * 8 + bx;     // dispatch order (x fastest)
    const int xcd = l & 7, s = l >> 3;   // s in [0,128)
    by = xcd * 16 + (s >> 3);      // XCD-exclusive 16-m-tile slab
    bx = s & 7;                    // n-fastest within slab
  }
  const int m0 = by * 128;
  const int n0 = bx * 128;

  // staging: 4 gload16/thread/tensor per K-tile (128 rows x 8 chunks).
  // c = i*256+t -> row=c>>3, ch=c&7; src chunk = ch^(row&7) (inverse of
  // the read-side XOR); LDS linear at c*16B (wave-uniform base + lane*16).
  const bf16* gA[4];
  const bf16* gB[4];
  int lds_off[4];                  // bf16 elements
#pragma unroll
  for (int i = 0; i < 4; ++i) {
    const int c = i*256 + t;
    const int row = c >> 3, ch = c & 7;
    const int sc = ch ^ (row & 7);
    gA[i] = Aptr + (size_t)(m0 + row)*K + sc*8;
    gB[i] = Bptr + (size_t)(n0 + row)*K + sc*8;
    lds_off[i] = (i*256 + w*64) * 8;
  }

  f32x4 acc[4][4] = {};

  for (int kt = 0; kt < K; kt += 64) {
    __syncthreads();               // prev tile's LDS reads done
#pragma unroll
    for (int i = 0; i < 4; ++i) gload16(gA[i] + kt, sA + lds_off[i]);
#pragma unroll
    for (int i = 0; i < 4; ++i) gload16(gB[i] + kt, sB + lds_off[i]);
    __syncthreads();               // compiler drains vmcnt before s_barrier
#pragma unroll
    for (int ks = 0; ks < 2; ++ks) {
      const int kc = ks*4 + quad;
      bf16x8 af[4], bv[4];
#pragma unroll
      for (int mi = 0; mi < 4; ++mi) {
        const int m = wm + mi*16 + lr;
        af[mi] = *(const bf16x8*)(sA + (m*8 + (kc ^ (m & 7)))*8);
      }
#pragma unroll
      for (int ni = 0; ni < 4; ++ni) {
        const int n = wn + ni*16 + lr;
        bv[ni] = *(const bf16x8*)(sB + (n*8 + (kc ^ (n & 7)))*8);
      }
#pragma unroll
      for (int mi = 0; mi < 4; ++mi)
#pragma unroll
        for (int ni = 0; ni < 4; ++ni)
          acc[mi][ni] = __builtin_amdgcn_mfma_f32_16x16x32_bf16(
              af[mi], bv[ni], acc[mi][ni], 0, 0, 0);
    }
  }

  __syncthreads();   // LDS reuse for epilogue

  // epilogue: per-wave 8 KiB LDS patch (32x64 f32), two halves, 16-B stores.
  const int f32out = args.force_f32 | (args.oflag ? *args.oflag : 0);
  float* sEw = (float*)(smem + w * 8192);
#pragma unroll
  for (int hh = 0; hh < 2; ++hh) {
    if (hh) asm volatile("s_waitcnt lgkmcnt(0)" ::: "memory");  // WAR vs hh=0 reads
#pragma unroll
    for (int mi2 = 0; mi2 < 2; ++mi2) {
      const int mi = hh*2 + mi2;
#pragma unroll
      for (int ni = 0; ni < 4; ++ni) {
        const int colg = n0 + wn + ni*16 + lr;
        const float bvv = args.bias ? (float)args.bias[colg] : 0.0f;
#pragma unroll
        for (int rg = 0; rg < 4; ++rg) {
          const int row = mi2*16 + quad*4 + rg;   // 0..31
          sEw[row*64 + ((ni*16 + lr) ^ ((row & 15)*4))] = acc[mi][ni][rg] + bvv;
        }
      }
    }
    asm volatile("s_waitcnt lgkmcnt(0)" ::: "memory");
#pragma unroll
    for (int i = 0; i < 4; ++i) {
      const int c = i*64 + lane;
      const int row = c >> 3, ch = c & 7;
      const int d0 = ch * 8;
      const int swz = (row & 15) * 4;
      f32x4 v0 = *(const f32x4*)(sEw + row*64 + (d0 ^ swz));
      f32x4 v1 = *(const f32x4*)(sEw + row*64 + ((d0 + 4) ^ swz));
      const size_t base = (size_t)(m0 + wm + hh*32 + row)*N + n0 + wn + d0;
      if (f32out) {
        *(f32x4*)((float*)Cptr + base)     = v0;
        *(f32x4*)((float*)Cptr + base + 4) = v1;
      } else {
        bf16x8 wv;
        wv[0]=(bf16)v0[0]; wv[1]=(bf16)v0[1]; wv[2]=(bf16)v0[2]; wv[3]=(bf16)v0[3];
        wv[4]=(bf16)v1[0]; wv[5]=(bf16)v1[1]; wv[6]=(bf16)v1[2]; wv[7]=(bf16)v1[3];
        *(bf16x8*)((bf16*)Cptr + base) = wv;
      }
    }
  }
}

// MFMA attention: per block one (b,h) x 128 Q-rows. (verified round 1)
__global__ __launch_bounds__(256, 2) void attn_mfma(
    const bf16* Q, const float* __restrict__ Klow,
    const float* __restrict__ Vlow, bf16* AO) {
  const int bh = blockIdx.x, b = bh >> 4, h = bh & 15;
  const int n0 = blockIdx.y * 128;

  __shared__ bf16 sQ[128*64];     // 16 KiB, gemm-swizzled
  __shared__ bf16 sKb[64*64];     // 8 KiB  [r][d] swizzled
  __shared__ bf16 sVt[64*64];     // 8 KiB  [d][r] swizzled (transposed)
  __shared__ bf16 sP[4][32*64];   // 16 KiB, per-wave

  const int t = threadIdx.x;
  const int lane = t & 63;
  const int w = t >> 6;
  const int lr = lane & 15;
  const int quad = lane >> 4;

#pragma unroll
  for (int i = 0; i < 4; ++i) {
    const int c = i*256 + t;
    const int row = c >> 3, j = c & 7;
    const uint4 v = *(const uint4*)(Q + ((size_t)b*NB + n0 + row)*DB + h*64 + j*8);
    *(uint4*)(sQ + (row*8 + (j ^ (row & 7)))*8) = v;
  }
  {
    const int r = t >> 2, c0 = (t & 3) * 16;
    const float* kb = Klow + (size_t)(b*64 + r)*DB + h*64 + c0;
    const float* vb = Vlow + (size_t)(b*64 + r)*DB + h*64 + c0;
    float kf[16], vf[16];
#pragma unroll
    for (int i = 0; i < 4; ++i) {
      *(f32x4*)(kf + i*4) = *(const f32x4*)(kb + i*4);
      *(f32x4*)(vf + i*4) = *(const f32x4*)(vb + i*4);
    }
#pragma unroll
    for (int cc = 0; cc < 2; ++cc) {
      bf16x8 pk;
#pragma unroll
      for (int j2 = 0; j2 < 8; ++j2) pk[j2] = (bf16)kf[cc*8 + j2];
      const int ch = (c0 >> 3) + cc;
      *(bf16x8*)(sKb + (r*8 + (ch ^ (r & 7)))*8) = pk;
    }
#pragma unroll
    for (int j2 = 0; j2 < 16; ++j2) {
      const int d = c0 + j2;
      sVt[d*64 + (((r >> 3) ^ (d & 7))*8) + (r & 7)] = (bf16)vf[j2];
    }
  }
  __syncthreads();

  f32x4 accS[2][4] = {};
#pragma unroll
  for (int ks = 0; ks < 2; ++ks) {
    const int kc = ks*4 + quad;
    bf16x8 af[2], bv[4];
#pragma unroll
    for (int mi = 0; mi < 2; ++mi) {
      const int m = w*32 + mi*16 + lr;
      af[mi] = *(const bf16x8*)(sQ + (m*8 + (kc ^ (m & 7)))*8);
    }
#pragma unroll
    for (int ni = 0; ni < 4; ++ni) {
      const int r = ni*16 + lr;
      bv[ni] = *(const bf16x8*)(sKb + (r*8 + (kc ^ (r & 7)))*8);
    }
#pragma unroll
    for (int mi = 0; mi < 2; ++mi)
#pragma unroll
      for (int ni = 0; ni < 4; ++ni)
        accS[mi][ni] = __builtin_amdgcn_mfma_f32_16x16x32_bf16(
            af[mi], bv[ni], accS[mi][ni], 0, 0, 0);
  }

  float inv_[2][4];
#pragma unroll
  for (int mi = 0; mi < 2; ++mi)
#pragma unroll
    for (int rg = 0; rg < 4; ++rg) {
      float mv = -3.0e38f;
#pragma unroll
      for (int ni = 0; ni < 4; ++ni) mv = fmaxf(mv, accS[mi][ni][rg]);
#pragma unroll
      for (int d = 1; d < 16; d <<= 1) mv = fmaxf(mv, __shfl_xor(mv, d));
      float sum = 0.0f;
#pragma unroll
      for (int ni = 0; ni < 4; ++ni) {
        const float p = __expf((accS[mi][ni][rg] - mv) * 0.125f);
        accS[mi][ni][rg] = p;
        sum += p;
      }
#pragma unroll
      for (int d = 1; d < 16; d <<= 1) sum += __shfl_xor(sum, d);
      inv_[mi][rg] = 1.0f / sum;   // applied at O-write (PV is linear)
    }

  bf16* myP = sP[w];
#pragma unroll
  for (int mi = 0; mi < 2; ++mi)
#pragma unroll
    for (int ni = 0; ni < 4; ++ni)
#pragma unroll
      for (int rg = 0; rg < 4; ++rg) {
        const int row = mi*16 + quad*4 + rg;
        const int col = ni*16 + lr;
        myP[row*64 + ((col >> 3) ^ (row & 7))*8 + (col & 7)] = (bf16)accS[mi][ni][rg];
      }

  f32x4 accO[2][4] = {};
#pragma unroll
  for (int ks = 0; ks < 2; ++ks) {
    const int kc = ks*4 + quad;
    bf16x8 ap[2], bvv[4];
#pragma unroll
    for (int mi = 0; mi < 2; ++mi) {
      const int m = mi*16 + lr;
      ap[mi] = *(const bf16x8*)(myP + (m*8 + (kc ^ (m & 7)))*8);
    }
#pragma unroll
    for (int di = 0; di < 4; ++di) {
      const int d = di*16 + lr;
      bvv[di] = *(const bf16x8*)(sVt + (d*8 + (kc ^ (d & 7)))*8);
    }
#pragma unroll
    for (int mi = 0; mi < 2; ++mi)
#pragma unroll
      for (int di = 0; di < 4; ++di)
        accO[mi][di] = __builtin_amdgcn_mfma_f32_16x16x32_bf16(
            ap[mi], bvv[di], accO[mi][di], 0, 0, 0);
  }

#pragma unroll
  for (int mi = 0; mi < 2; ++mi)
#pragma unroll
    for (int di = 0; di < 4; ++di)
#pragma unroll
      for (int rg = 0; rg < 4; ++rg) {
        const int row = mi*16 + quad*4 + rg;     // 0..31
        const int col = di*16 + lr;              // 0..63
        myP[row*64 + ((col >> 3) ^ (row & 7))*8 + (col & 7)] =
            (bf16)(accO[mi][di][rg] * inv_[mi][rg]);
      }
  asm volatile("s_waitcnt lgkmcnt(0)" ::: "memory");
#pragma unroll
  for (int i = 0; i < 4; ++i) {
    const int c = i*64 + lane;
    const int row = c >> 3, ch = c & 7;
    const bf16x8 v = *(const bf16x8*)(myP + row*64 + ((ch ^ (row & 7))*8));
    *(bf16x8*)(AO + ((size_t)b*NB + n0 + w*32 + row)*DB + h*64 + ch*8) = v;
  }
}

extern "C" void kernel_launch(void* const* d_in, const int* in_sizes, int n_in,
                              void* d_out, int out_size, void* d_ws, size_t ws_size,
                              hipStream_t stream) {
  char* ws = (char*)d_ws;
  const size_t MiB = 1024*1024;
  int*   flag = (int*)ws;
  float* Klow = (float*)(ws + 1*MiB);
  float* Vlow = (float*)(ws + 2*MiB);
  bf16*  xEb  = (bf16*)(ws + 3*MiB);
  bf16*  xFb  = (bf16*)(ws + 3*MiB + 512*1024);
  bf16*  EFt  = (bf16*)(ws + 4*MiB);
  bf16*  Wqb  = (bf16*)(ws + 7*MiB);
  bf16*  Wkb  = (bf16*)(ws + 9*MiB);
  bf16*  Wvb  = (bf16*)(ws + 11*MiB);
  bf16*  Wob  = (bf16*)(ws + 13*MiB);
  bf16*  bob  = (bf16*)(ws + 15*MiB);
  bf16*  xb   = (bf16*)(ws + 20*MiB);
  bf16*  S0   = (bf16*)(ws + 52*MiB);
  // Pf (16 MiB) aliases S0's region: written by lowrank_mfma, consumed by
  // lowrank_reduce, both strictly before the Q-GEMM writes S0 (one stream).
  float* Pf   = (float*)(ws + 52*MiB);

  detect_dtype<<<1, 256, 0, stream>>>((const unsigned short*)d_in[0], flag);

  ef_transpose<<<dim3(128), 256, 0, stream>>>(d_in[6], d_in[7], EFt, flag);

  CvtArgs ca;
  bf16* dsts[6] = {xb, Wqb, Wkb, Wvb, Wob, bob};
  int   ns[6]   = {16777216, 1048576, 1048576, 1048576, 1048576, 1024};
  int off = 0;
  for (int i = 0; i < 6; ++i) {
    ca.src[i] = d_in[i]; ca.dst[i] = dsts[i]; ca.n[i] = ns[i];
    ca.off[i] = off; off += (ns[i] + 2047) / 2048;
  }
  for (int i = 6; i < 8; ++i) {
    ca.src[i] = d_in[0]; ca.dst[i] = xb; ca.n[i] = 0; ca.off[i] = off;
  }
  ca.off[8] = off;
  to_bf16_multi<<<dim3(off), 256, 0, stream>>>(ca, flag);

  lowrank_mfma<<<dim3(4, 32, NSEG), 256, 0, stream>>>(EFt, xb, Pf);
  lowrank_reduce<<<dim3(512), 256, 0, stream>>>(Pf, xEb, xFb);

  GemmArgs ka;                       // dual: Klow = xE @ Wk^T ; Vlow = xF @ Wv^T
  ka.A = xEb; ka.B = Wkb; ka.C = Klow;
  ka.A2 = xFb; ka.B2 = Wvb; ka.C2 = Vlow;
  ka.dual = 1;
  ka.bias = nullptr; ka.oflag = nullptr; ka.force_f32 = 1;
  ka.M = 256; ka.N = DB; ka.K = DB;
  gemm_nt<<<dim3(8, 2, 2), 256, 0, stream>>>(ka);

  GemmArgs qa;                       // Q = x @ Wq^T
  qa.A = xb; qa.B = Wqb; qa.C = S0; qa.bias = nullptr;
  qa.oflag = nullptr; qa.force_f32 = 0;
  qa.A2 = nullptr; qa.B2 = nullptr; qa.C2 = nullptr; qa.dual = 0;
  qa.M = MB; qa.N = DB; qa.K = DB;
  gemm_nt<<<dim3(8, 128, 1), 256, 0, stream>>>(qa);

  attn_mfma<<<dim3(64, 32), 256, 0, stream>>>(S0, Klow, Vlow, S0);

  GemmArgs oa;                       // out = AO @ Wo^T + bo
  oa.A = S0; oa.B = Wob; oa.C = d_out; oa.bias = bob;
  oa.oflag = flag; oa.force_f32 = 0;
  oa.A2 = nullptr; oa.B2 = nullptr; oa.C2 = nullptr; oa.dual = 0;
  oa.M = MB; oa.N = DB; oa.K = DB;
  gemm_nt<<<dim3(8, 128, 1), 256, 0, stream>>>(oa);
}